// Round 1
// baseline (841.296 us; speedup 1.0000x reference)
//
#include <hip/hip_runtime.h>
#include <math.h>

__device__ __forceinline__ float leakyrelu02(float v) { return v > 0.f ? v : 0.2f * v; }

// ============ GEMM: C[M,256] = A[M,256] @ B[256,256], fp32 ============
__global__ __launch_bounds__(256) void k_gemm1(const float* __restrict__ A,
                                               const float* __restrict__ B,
                                               float* __restrict__ C, int M) {
  __shared__ float As[16][68];
  __shared__ float Bs[16][64];
  const int m0 = blockIdx.x * 64;
  const int n0 = blockIdx.y * 64;
  const int tid = threadIdx.x;
  const int tm = tid & 15, tn = tid >> 4;
  float acc[4][4];
#pragma unroll
  for (int i = 0; i < 4; ++i)
#pragma unroll
    for (int j = 0; j < 4; ++j) acc[i][j] = 0.f;

  const int am = tid & 63, ak = (tid >> 6) << 2;
  const int bk = tid >> 4, bn = (tid & 15) << 2;

  for (int k0 = 0; k0 < 256; k0 += 16) {
    float4 av = make_float4(0.f, 0.f, 0.f, 0.f);
    if (m0 + am < M) av = *(const float4*)(A + (size_t)(m0 + am) * 256 + (k0 + ak));
    As[ak + 0][am] = av.x;
    As[ak + 1][am] = av.y;
    As[ak + 2][am] = av.z;
    As[ak + 3][am] = av.w;
    float4 bv = *(const float4*)(B + (size_t)(k0 + bk) * 256 + (n0 + bn));
    *(float4*)&Bs[bk][bn] = bv;
    __syncthreads();
#pragma unroll
    for (int kk = 0; kk < 16; ++kk) {
      float a[4], b[4];
#pragma unroll
      for (int i = 0; i < 4; ++i) a[i] = As[kk][tm * 4 + i];
#pragma unroll
      for (int j = 0; j < 4; ++j) b[j] = Bs[kk][tn * 4 + j];
#pragma unroll
      for (int i = 0; i < 4; ++i)
#pragma unroll
        for (int j = 0; j < 4; ++j) acc[i][j] += a[i] * b[j];
    }
    __syncthreads();
  }
#pragma unroll
  for (int i = 0; i < 4; ++i) {
    int m = m0 + tm * 4 + i;
    if (m < M) {
      float4 o = make_float4(acc[i][0], acc[i][1], acc[i][2], acc[i][3]);
      *(float4*)(C + (size_t)m * 256 + (n0 + tn * 4)) = o;
    }
  }
}

// ============ attention logits for layer 1: wave per node ============
__global__ __launch_bounds__(256) void k_al1(const float* __restrict__ h_lin,
                                             const float* __restrict__ a_src,
                                             const float* __restrict__ a_dst,
                                             float* __restrict__ als,
                                             float* __restrict__ ald, int N) {
  int gid = blockIdx.x * 256 + threadIdx.x;
  int n = gid >> 6;
  int l = threadIdx.x & 63;
  if (n >= N) return;
  float4 h4 = *(const float4*)(h_lin + (size_t)n * 256 + l * 4);
  float4 vs = *(const float4*)(a_src + l * 4);
  float4 vd = *(const float4*)(a_dst + l * 4);
  float ps = h4.x * vs.x + h4.y * vs.y + h4.z * vs.z + h4.w * vs.w;
  float pd = h4.x * vd.x + h4.y * vd.y + h4.z * vd.z + h4.w * vd.w;
  ps += __shfl_xor(ps, 1); pd += __shfl_xor(pd, 1);
  ps += __shfl_xor(ps, 2); pd += __shfl_xor(pd, 2);
  ps += __shfl_xor(ps, 4); pd += __shfl_xor(pd, 4);
  if ((l & 7) == 0) {
    als[(size_t)n * 8 + (l >> 3)] = ps;
    ald[(size_t)n * 8 + (l >> 3)] = pd;
  }
}

// ============ CSR build ============
__global__ __launch_bounds__(256) void k_hist(const int* __restrict__ ei,
                                              int* __restrict__ counts, int E, int N) {
  int e = blockIdx.x * 256 + threadIdx.x;
  if (e >= E + N) return;
  int d = (e < E) ? ei[E + e] : (e - E);
  atomicAdd(&counts[d], 1);
}

__global__ __launch_bounds__(1024) void k_scan(const int* __restrict__ counts,
                                               int* __restrict__ offsets,
                                               int* __restrict__ cursor, int N) {
  __shared__ int part[1024];
  const int t = threadIdx.x;
  const int chunk = (N + 1023) / 1024;
  const int base = t * chunk;
  int ssum = 0;
  for (int i = 0; i < chunk; ++i) {
    int idx = base + i;
    if (idx < N) ssum += counts[idx];
  }
  part[t] = ssum;
  __syncthreads();
  for (int d = 1; d < 1024; d <<= 1) {
    int v = (t >= d) ? part[t - d] : 0;
    __syncthreads();
    part[t] += v;
    __syncthreads();
  }
  int run = (t == 0) ? 0 : part[t - 1];
  for (int i = 0; i < chunk; ++i) {
    int idx = base + i;
    if (idx < N) {
      offsets[idx] = run;
      cursor[idx] = run;
      run += counts[idx];
    }
  }
  if (t == 1023) offsets[N] = run;
}

__global__ __launch_bounds__(256) void k_scatter(const int* __restrict__ ei,
                                                 int* __restrict__ cursor,
                                                 int* __restrict__ csr_src, int E, int N) {
  int e = blockIdx.x * 256 + threadIdx.x;
  if (e >= E + N) return;
  int d, s;
  if (e < E) { d = ei[E + e]; s = ei[e]; }
  else { d = e - E; s = e - E; }
  int pos = atomicAdd(&cursor[d], 1);
  csr_src[pos] = s;
}

// ============ GAT layer 1 aggregation + fused (relu row) @ W2 -> h2, al2 ============
__global__ __launch_bounds__(256) void k_gat1(
    const float* __restrict__ h_lin, const float* __restrict__ als1,
    const float* __restrict__ ald1, const float* __restrict__ b1,
    const int* __restrict__ offsets, const int* __restrict__ csr_src,
    const float* __restrict__ W2, const float* __restrict__ a_src2,
    const float* __restrict__ a_dst2, float* __restrict__ h2,
    float* __restrict__ als2, float* __restrict__ ald2, int N) {
  __shared__ float w2s[4096];
  __shared__ float rowbuf[4][256];
  for (int i = threadIdx.x; i < 4096; i += 256) w2s[i] = W2[i];
  __syncthreads();

  const int w = threadIdx.x >> 6;
  const int l = threadIdx.x & 63;
  const int n = blockIdx.x * 4 + w;
  if (n >= N) return;

  const int off = offsets[n];
  const int deg = offsets[n + 1] - off;

  const int h1 = l & 7;
  const int slot = l >> 3;
  const float adl = ald1[(size_t)n * 8 + h1];

  // pass 1: per-head max over incoming edges
  float mx = -INFINITY;
  for (int e0 = 0; e0 < deg; e0 += 8) {
    int e = e0 + slot;
    if (e < deg) {
      int s = csr_src[off + e];
      float v = leakyrelu02(als1[(size_t)s * 8 + h1] + adl);
      mx = fmaxf(mx, v);
    }
  }
  mx = fmaxf(mx, __shfl_xor(mx, 8));
  mx = fmaxf(mx, __shfl_xor(mx, 16));
  mx = fmaxf(mx, __shfl_xor(mx, 32));

  // pass 2: denominator
  float sm = 0.f;
  for (int e0 = 0; e0 < deg; e0 += 8) {
    int e = e0 + slot;
    if (e < deg) {
      int s = csr_src[off + e];
      float v = leakyrelu02(als1[(size_t)s * 8 + h1] + adl);
      sm += expf(v - mx);
    }
  }
  sm += __shfl_xor(sm, 8);
  sm += __shfl_xor(sm, 16);
  sm += __shfl_xor(sm, 32);
  const float inv = 1.f / (sm + 1e-16f);

  // rearrange per-head stats: lane's channels l*4.. belong to head l>>3
  const int h3 = l >> 3;
  const float mh = __shfl(mx, h3);
  const float ih = __shfl(inv, h3);
  const float ad3 = __shfl(adl, h3);

  // pass 3: weighted aggregation of h_lin[src]
  float ax = 0.f, ay = 0.f, az = 0.f, aw2 = 0.f;
  for (int e = 0; e < deg; ++e) {
    int s = csr_src[off + e];
    float v = leakyrelu02(als1[(size_t)s * 8 + h3] + ad3);
    float alpha = expf(v - mh) * ih;
    float4 hv = *(const float4*)(h_lin + (size_t)s * 256 + l * 4);
    ax += alpha * hv.x; ay += alpha * hv.y; az += alpha * hv.z; aw2 += alpha * hv.w;
  }
  float4 bb = *(const float4*)(b1 + l * 4);
  rowbuf[w][l * 4 + 0] = fmaxf(ax + bb.x, 0.f);
  rowbuf[w][l * 4 + 1] = fmaxf(ay + bb.y, 0.f);
  rowbuf[w][l * 4 + 2] = fmaxf(az + bb.z, 0.f);
  rowbuf[w][l * 4 + 3] = fmaxf(aw2 + bb.w, 0.f);
  asm volatile("s_waitcnt lgkmcnt(0)" ::: "memory");

  // h2[n,o] = sum_cc relu_row[cc] * W2[cc,o] : lane l -> o = l&15, grp = l>>4
  const int o = l & 15;
  const int grp = l >> 4;
  float a2 = 0.f;
#pragma unroll 8
  for (int t = 0; t < 64; ++t) {
    a2 += rowbuf[w][grp * 64 + t] * w2s[(grp * 64 + t) * 16 + o];
  }
  a2 += __shfl_xor(a2, 16);
  a2 += __shfl_xor(a2, 32);

  if (l < 16) {
    h2[(size_t)n * 16 + l] = a2;
    float ps = a2 * a_src2[l];
    float pd = a2 * a_dst2[l];
    ps += __shfl_xor(ps, 1); pd += __shfl_xor(pd, 1);
    ps += __shfl_xor(ps, 2); pd += __shfl_xor(pd, 2);
    ps += __shfl_xor(ps, 4); pd += __shfl_xor(pd, 4);
    ps += __shfl_xor(ps, 8); pd += __shfl_xor(pd, 8);
    if (l == 0) { als2[n] = ps; ald2[n] = pd; }
  }
}

// ============ GAT layer 2 aggregation -> x1, g, sortable keys ============
__global__ __launch_bounds__(256) void k_gat2(
    const float* __restrict__ h2, const float* __restrict__ als2,
    const float* __restrict__ ald2, const float* __restrict__ b2,
    const float* __restrict__ proj_w, const float* __restrict__ proj_b,
    const int* __restrict__ offsets, const int* __restrict__ csr_src,
    float* __restrict__ x1, float* __restrict__ g,
    unsigned long long* __restrict__ keys, int N) {
  const int w = threadIdx.x >> 6;
  const int l = threadIdx.x & 63;
  const int n = blockIdx.x * 4 + w;
  if (n >= N) return;
  const int off = offsets[n];
  const int deg = offsets[n + 1] - off;
  const float ad = ald2[n];

  float mx = -INFINITY;
  for (int e0 = 0; e0 < deg; e0 += 64) {
    int e = e0 + l;
    if (e < deg) {
      float v = leakyrelu02(als2[csr_src[off + e]] + ad);
      mx = fmaxf(mx, v);
    }
  }
#pragma unroll
  for (int d = 1; d < 64; d <<= 1) mx = fmaxf(mx, __shfl_xor(mx, d));

  float sm = 0.f;
  for (int e0 = 0; e0 < deg; e0 += 64) {
    int e = e0 + l;
    if (e < deg) {
      float v = leakyrelu02(als2[csr_src[off + e]] + ad);
      sm += expf(v - mx);
    }
  }
#pragma unroll
  for (int d = 1; d < 64; d <<= 1) sm += __shfl_xor(sm, d);
  const float inv = 1.f / (sm + 1e-16f);

  const int slot = l >> 4;
  const int c = l & 15;
  float acc = 0.f;
  for (int e0 = 0; e0 < deg; e0 += 4) {
    int e = e0 + slot;
    if (e < deg) {
      int s = csr_src[off + e];
      float v = leakyrelu02(als2[s] + ad);
      float alpha = expf(v - mx) * inv;
      acc += alpha * h2[(size_t)s * 16 + c];
    }
  }
  acc += __shfl_xor(acc, 16);
  acc += __shfl_xor(acc, 32);
  float x1v = acc + b2[c];
  float pg = (l < 16) ? x1v * proj_w[c] : 0.f;
#pragma unroll
  for (int d = 1; d < 64; d <<= 1) pg += __shfl_xor(pg, d);
  if (l < 16) x1[(size_t)n * 16 + l] = x1v;
  if (l == 0) {
    float gv = pg + proj_b[0];
    g[n] = gv;
    unsigned u = __float_as_uint(gv);
    u = (u & 0x80000000u) ? ~u : (u | 0x80000000u);
    keys[n] = (((unsigned long long)u) << 32) | (unsigned)n;
  }
}

// ============ brute-force exact stable rank (argsort) ============
__global__ __launch_bounds__(256) void k_rank(const unsigned long long* __restrict__ keys,
                                              int* __restrict__ rank, int N, int jchunk) {
  __shared__ unsigned long long kt[2048];
  const int i = blockIdx.x * 256 + threadIdx.x;
  const unsigned long long ki = (i < N) ? keys[i] : ~0ull;
  const int jbeg = blockIdx.y * jchunk;
  const int jend = min(N, jbeg + jchunk);
  int r = 0;
  for (int t0 = jbeg; t0 < jend; t0 += 2048) {
    int cnt = min(2048, jend - t0);
    __syncthreads();
    for (int t = threadIdx.x; t < cnt; t += 256) kt[t] = keys[t0 + t];
    __syncthreads();
#pragma unroll 4
    for (int t = 0; t < cnt; ++t) r += (kt[t] < ki) ? 1 : 0;
  }
  if (i < N) atomicAdd(&rank[i], r);
}

// ============ scatter g*x1 into sorted order ============
__global__ __launch_bounds__(256) void k_scatter_sorted(
    const float* __restrict__ g, const float* __restrict__ x1,
    const int* __restrict__ rank, float* __restrict__ sortedv, int N) {
  int n = blockIdx.x * 256 + threadIdx.x;
  if (n >= N) return;
  int r = rank[n];
  float gv = g[n];
#pragma unroll
  for (int c = 0; c < 16; c += 4) {
    float4 v = *(const float4*)(x1 + (size_t)n * 16 + c);
    float4 o = make_float4(gv * v.x, gv * v.y, gv * v.z, gv * v.w);
    *(float4*)(sortedv + (size_t)r * 16 + c) = o;
  }
}

// ============ conv1d 'same', K=5, 16->16 channels ============
__global__ __launch_bounds__(256) void k_conv(const float* __restrict__ in,
                                              const float* __restrict__ wgt,
                                              const float* __restrict__ bias,
                                              float* __restrict__ out, int N, int relu) {
  __shared__ float s[260][17];
  __shared__ float ws[1280];
  __shared__ float bs[16];
  const int p0 = blockIdx.x * 256;
  for (int i = threadIdx.x; i < 1280; i += 256) ws[i] = wgt[i];
  if (threadIdx.x < 16) bs[threadIdx.x] = bias[threadIdx.x];
  for (int idx = threadIdx.x; idx < 260 * 16; idx += 256) {
    int lp = idx >> 4, c = idx & 15;
    int gp = p0 - 2 + lp;
    s[lp][c] = (gp >= 0 && gp < N) ? in[(size_t)gp * 16 + c] : 0.f;
  }
  __syncthreads();
  const int p = p0 + threadIdx.x;
  if (p >= N) return;
  float acc[16];
#pragma unroll
  for (int o = 0; o < 16; ++o) acc[o] = bs[o];
  for (int k = 0; k < 5; ++k) {
    for (int c = 0; c < 16; ++c) {
      float xv = s[threadIdx.x + k][c];
#pragma unroll
      for (int o = 0; o < 16; ++o) acc[o] += ws[(o * 16 + c) * 5 + k] * xv;
    }
  }
#pragma unroll
  for (int o = 0; o < 16; ++o) {
    float v = acc[o];
    if (relu) v = fmaxf(v, 0.f);
    out[(size_t)p * 16 + o] = v;
  }
}

// ============ final: concat(x1, x2=conv2[rank]) @ lin_w + lin_b -> log_softmax ============
__global__ __launch_bounds__(256) void k_final(
    const float* __restrict__ x1, const float* __restrict__ c2out,
    const int* __restrict__ rank, const float* __restrict__ lin_w,
    const float* __restrict__ lin_b, float* __restrict__ out, int N) {
  __shared__ float lw[512];
  __shared__ float lb[16];
  for (int i = threadIdx.x; i < 512; i += 256) lw[i] = lin_w[i];
  if (threadIdx.x < 16) lb[threadIdx.x] = lin_b[threadIdx.x];
  __syncthreads();
  const int n = blockIdx.x * 256 + threadIdx.x;
  if (n >= N) return;
  float xa[16], xb[16];
  const int r = rank[n];
#pragma unroll
  for (int c = 0; c < 16; c += 4) {
    float4 va = *(const float4*)(x1 + (size_t)n * 16 + c);
    float4 vb = *(const float4*)(c2out + (size_t)r * 16 + c);
    xa[c] = va.x; xa[c + 1] = va.y; xa[c + 2] = va.z; xa[c + 3] = va.w;
    xb[c] = vb.x; xb[c + 1] = vb.y; xb[c + 2] = vb.z; xb[c + 3] = vb.w;
  }
  float z[16];
#pragma unroll
  for (int o = 0; o < 16; ++o) z[o] = lb[o];
#pragma unroll
  for (int c = 0; c < 16; ++c) {
    float va = xa[c], vb = xb[c];
#pragma unroll
    for (int o = 0; o < 16; ++o) z[o] += va * lw[c * 16 + o] + vb * lw[(16 + c) * 16 + o];
  }
  float m = z[0];
#pragma unroll
  for (int o = 1; o < 16; ++o) m = fmaxf(m, z[o]);
  float ssum = 0.f;
#pragma unroll
  for (int o = 0; o < 16; ++o) ssum += expf(z[o] - m);
  float lse = m + logf(ssum);
#pragma unroll
  for (int o = 0; o < 16; ++o) out[(size_t)n * 16 + o] = z[o] - lse;
}

extern "C" void kernel_launch(void* const* d_in, const int* in_sizes, int n_in,
                              void* d_out, int out_size, void* d_ws, size_t ws_size,
                              hipStream_t stream) {
  const float* x = (const float*)d_in[0];
  const int* ei = (const int*)d_in[1];
  const float* W1 = (const float*)d_in[2];
  const float* a_src1 = (const float*)d_in[3];
  const float* a_dst1 = (const float*)d_in[4];
  const float* b1 = (const float*)d_in[5];
  const float* W2 = (const float*)d_in[6];
  const float* a_src2 = (const float*)d_in[7];
  const float* a_dst2 = (const float*)d_in[8];
  const float* b2 = (const float*)d_in[9];
  const float* proj_w = (const float*)d_in[10];
  const float* proj_b = (const float*)d_in[11];
  const float* c1_w = (const float*)d_in[12];
  const float* c1_b = (const float*)d_in[13];
  const float* c2_w = (const float*)d_in[14];
  const float* c2_b = (const float*)d_in[15];
  const float* lin_w = (const float*)d_in[16];
  const float* lin_b = (const float*)d_in[17];
  float* out = (float*)d_out;

  const int N = in_sizes[0] / 256;
  const int E = in_sizes[1] / 2;
  const int Etot = E + N;

  char* ws = (char*)d_ws;
  size_t off = 0;
  auto alloc = [&](size_t bytes) -> void* {
    void* p = ws + off;
    off = (off + bytes + 255) & ~(size_t)255;
    return p;
  };
  float* h_lin = (float*)alloc((size_t)N * 256 * 4);
  float* als1 = (float*)alloc((size_t)N * 8 * 4);
  float* ald1 = (float*)alloc((size_t)N * 8 * 4);
  int* counts = (int*)alloc((size_t)N * 4);
  int* offsets = (int*)alloc((size_t)(N + 1) * 4);
  int* cursor = (int*)alloc((size_t)N * 4);
  int* csr_src = (int*)alloc((size_t)Etot * 4);
  float* h2 = (float*)alloc((size_t)N * 16 * 4);
  float* als2 = (float*)alloc((size_t)N * 4);
  float* ald2 = (float*)alloc((size_t)N * 4);
  float* x1 = (float*)alloc((size_t)N * 16 * 4);
  float* gbuf = (float*)alloc((size_t)N * 4);
  unsigned long long* keys = (unsigned long long*)alloc((size_t)N * 8);
  int* rank = (int*)alloc((size_t)N * 4);
  float* sortedv = (float*)alloc((size_t)N * 16 * 4);
  float* c1out = (float*)alloc((size_t)N * 16 * 4);
  float* c2out = (float*)alloc((size_t)N * 16 * 4);
  if (off > ws_size) return;  // fail loudly (poisoned output) rather than corrupt memory

  hipMemsetAsync(counts, 0, (size_t)N * 4, stream);
  hipMemsetAsync(rank, 0, (size_t)N * 4, stream);

  dim3 gg((N + 63) / 64, 4);
  k_gemm1<<<gg, 256, 0, stream>>>(x, W1, h_lin, N);
  k_al1<<<(N + 3) / 4, 256, 0, stream>>>(h_lin, a_src1, a_dst1, als1, ald1, N);
  k_hist<<<(Etot + 255) / 256, 256, 0, stream>>>(ei, counts, E, N);
  k_scan<<<1, 1024, 0, stream>>>(counts, offsets, cursor, N);
  k_scatter<<<(Etot + 255) / 256, 256, 0, stream>>>(ei, cursor, csr_src, E, N);
  k_gat1<<<(N + 3) / 4, 256, 0, stream>>>(h_lin, als1, ald1, b1, offsets, csr_src,
                                          W2, a_src2, a_dst2, h2, als2, ald2, N);
  k_gat2<<<(N + 3) / 4, 256, 0, stream>>>(h2, als2, ald2, b2, proj_w, proj_b,
                                          offsets, csr_src, x1, gbuf, keys, N);
  const int jchunk = (N + 3) / 4;
  dim3 gr((N + 255) / 256, 4);
  k_rank<<<gr, 256, 0, stream>>>(keys, rank, N, jchunk);
  k_scatter_sorted<<<(N + 255) / 256, 256, 0, stream>>>(gbuf, x1, rank, sortedv, N);
  k_conv<<<(N + 255) / 256, 256, 0, stream>>>(sortedv, c1_w, c1_b, c1out, N, 1);
  k_conv<<<(N + 255) / 256, 256, 0, stream>>>(c1out, c2_w, c2_b, c2out, N, 0);
  k_final<<<(N + 255) / 256, 256, 0, stream>>>(x1, c2out, rank, lin_w, lin_b, out, N);
}

// Round 2
// 755.253 us; speedup vs baseline: 1.1139x; 1.1139x over previous
//
#include <hip/hip_runtime.h>
#include <math.h>

__device__ __forceinline__ float leakyrelu02(float v) { return v > 0.f ? v : 0.2f * v; }

// ============ GEMM: C[M,256] = A[M,256] @ B[256,256], fp32 ============
__global__ __launch_bounds__(256) void k_gemm1(const float* __restrict__ A,
                                               const float* __restrict__ B,
                                               float* __restrict__ C, int M) {
  __shared__ float As[16][68];
  __shared__ float Bs[16][64];
  const int m0 = blockIdx.x * 64;
  const int n0 = blockIdx.y * 64;
  const int tid = threadIdx.x;
  const int tm = tid & 15, tn = tid >> 4;
  float acc[4][4];
#pragma unroll
  for (int i = 0; i < 4; ++i)
#pragma unroll
    for (int j = 0; j < 4; ++j) acc[i][j] = 0.f;

  const int am = tid & 63, ak = (tid >> 6) << 2;
  const int bk = tid >> 4, bn = (tid & 15) << 2;

  for (int k0 = 0; k0 < 256; k0 += 16) {
    float4 av = make_float4(0.f, 0.f, 0.f, 0.f);
    if (m0 + am < M) av = *(const float4*)(A + (size_t)(m0 + am) * 256 + (k0 + ak));
    As[ak + 0][am] = av.x;
    As[ak + 1][am] = av.y;
    As[ak + 2][am] = av.z;
    As[ak + 3][am] = av.w;
    float4 bv = *(const float4*)(B + (size_t)(k0 + bk) * 256 + (n0 + bn));
    *(float4*)&Bs[bk][bn] = bv;
    __syncthreads();
#pragma unroll
    for (int kk = 0; kk < 16; ++kk) {
      float a[4], b[4];
#pragma unroll
      for (int i = 0; i < 4; ++i) a[i] = As[kk][tm * 4 + i];
#pragma unroll
      for (int j = 0; j < 4; ++j) b[j] = Bs[kk][tn * 4 + j];
#pragma unroll
      for (int i = 0; i < 4; ++i)
#pragma unroll
        for (int j = 0; j < 4; ++j) acc[i][j] += a[i] * b[j];
    }
    __syncthreads();
  }
#pragma unroll
  for (int i = 0; i < 4; ++i) {
    int m = m0 + tm * 4 + i;
    if (m < M) {
      float4 o = make_float4(acc[i][0], acc[i][1], acc[i][2], acc[i][3]);
      *(float4*)(C + (size_t)m * 256 + (n0 + tn * 4)) = o;
    }
  }
}

// ============ attention logits for layer 1: wave per node ============
__global__ __launch_bounds__(256) void k_al1(const float* __restrict__ h_lin,
                                             const float* __restrict__ a_src,
                                             const float* __restrict__ a_dst,
                                             float* __restrict__ als,
                                             float* __restrict__ ald, int N) {
  int gid = blockIdx.x * 256 + threadIdx.x;
  int n = gid >> 6;
  int l = threadIdx.x & 63;
  if (n >= N) return;
  float4 h4 = *(const float4*)(h_lin + (size_t)n * 256 + l * 4);
  float4 vs = *(const float4*)(a_src + l * 4);
  float4 vd = *(const float4*)(a_dst + l * 4);
  float ps = h4.x * vs.x + h4.y * vs.y + h4.z * vs.z + h4.w * vs.w;
  float pd = h4.x * vd.x + h4.y * vd.y + h4.z * vd.z + h4.w * vd.w;
  ps += __shfl_xor(ps, 1); pd += __shfl_xor(pd, 1);
  ps += __shfl_xor(ps, 2); pd += __shfl_xor(pd, 2);
  ps += __shfl_xor(ps, 4); pd += __shfl_xor(pd, 4);
  if ((l & 7) == 0) {
    als[(size_t)n * 8 + (l >> 3)] = ps;
    ald[(size_t)n * 8 + (l >> 3)] = pd;
  }
}

// ============ CSR build ============
__global__ __launch_bounds__(256) void k_hist(const int* __restrict__ ei,
                                              int* __restrict__ counts, int E, int N) {
  int e = blockIdx.x * 256 + threadIdx.x;
  if (e >= E + N) return;
  int d = (e < E) ? ei[E + e] : (e - E);
  atomicAdd(&counts[d], 1);
}

__global__ __launch_bounds__(1024) void k_scan(const int* __restrict__ counts,
                                               int* __restrict__ offsets,
                                               int* __restrict__ cursor, int N) {
  __shared__ int part[1024];
  const int t = threadIdx.x;
  const int chunk = (N + 1023) / 1024;
  const int base = t * chunk;
  int ssum = 0;
  for (int i = 0; i < chunk; ++i) {
    int idx = base + i;
    if (idx < N) ssum += counts[idx];
  }
  part[t] = ssum;
  __syncthreads();
  for (int d = 1; d < 1024; d <<= 1) {
    int v = (t >= d) ? part[t - d] : 0;
    __syncthreads();
    part[t] += v;
    __syncthreads();
  }
  int run = (t == 0) ? 0 : part[t - 1];
  for (int i = 0; i < chunk; ++i) {
    int idx = base + i;
    if (idx < N) {
      offsets[idx] = run;
      cursor[idx] = run;
      run += counts[idx];
    }
  }
  if (t == 1023) offsets[N] = run;
}

__global__ __launch_bounds__(256) void k_scatter(const int* __restrict__ ei,
                                                 int* __restrict__ cursor,
                                                 int* __restrict__ csr_src, int E, int N) {
  int e = blockIdx.x * 256 + threadIdx.x;
  if (e >= E + N) return;
  int d, s;
  if (e < E) { d = ei[E + e]; s = ei[e]; }
  else { d = e - E; s = e - E; }
  int pos = atomicAdd(&cursor[d], 1);
  csr_src[pos] = s;
}

// ============ GAT layer 1 aggregation + fused (relu row) @ W2 -> h2, al2 ============
__global__ __launch_bounds__(256) void k_gat1(
    const float* __restrict__ h_lin, const float* __restrict__ als1,
    const float* __restrict__ ald1, const float* __restrict__ b1,
    const int* __restrict__ offsets, const int* __restrict__ csr_src,
    const float* __restrict__ W2, const float* __restrict__ a_src2,
    const float* __restrict__ a_dst2, float* __restrict__ h2,
    float* __restrict__ als2, float* __restrict__ ald2, int N) {
  __shared__ float w2s[4096];
  __shared__ float rowbuf[4][256];
  for (int i = threadIdx.x; i < 4096; i += 256) w2s[i] = W2[i];
  __syncthreads();

  const int w = threadIdx.x >> 6;
  const int l = threadIdx.x & 63;
  const int n = blockIdx.x * 4 + w;
  if (n >= N) return;

  const int off = offsets[n];
  const int deg = offsets[n + 1] - off;

  const int h1 = l & 7;
  const int slot = l >> 3;
  const float adl = ald1[(size_t)n * 8 + h1];

  // pass 1: per-head max over incoming edges
  float mx = -INFINITY;
  for (int e0 = 0; e0 < deg; e0 += 8) {
    int e = e0 + slot;
    if (e < deg) {
      int s = csr_src[off + e];
      float v = leakyrelu02(als1[(size_t)s * 8 + h1] + adl);
      mx = fmaxf(mx, v);
    }
  }
  mx = fmaxf(mx, __shfl_xor(mx, 8));
  mx = fmaxf(mx, __shfl_xor(mx, 16));
  mx = fmaxf(mx, __shfl_xor(mx, 32));

  // pass 2: denominator
  float sm = 0.f;
  for (int e0 = 0; e0 < deg; e0 += 8) {
    int e = e0 + slot;
    if (e < deg) {
      int s = csr_src[off + e];
      float v = leakyrelu02(als1[(size_t)s * 8 + h1] + adl);
      sm += expf(v - mx);
    }
  }
  sm += __shfl_xor(sm, 8);
  sm += __shfl_xor(sm, 16);
  sm += __shfl_xor(sm, 32);
  const float inv = 1.f / (sm + 1e-16f);

  // rearrange per-head stats: lane's channels l*4.. belong to head l>>3
  const int h3 = l >> 3;
  const float mh = __shfl(mx, h3);
  const float ih = __shfl(inv, h3);
  const float ad3 = __shfl(adl, h3);

  // pass 3: weighted aggregation of h_lin[src]
  float ax = 0.f, ay = 0.f, az = 0.f, aw2 = 0.f;
  for (int e = 0; e < deg; ++e) {
    int s = csr_src[off + e];
    float v = leakyrelu02(als1[(size_t)s * 8 + h3] + ad3);
    float alpha = expf(v - mh) * ih;
    float4 hv = *(const float4*)(h_lin + (size_t)s * 256 + l * 4);
    ax += alpha * hv.x; ay += alpha * hv.y; az += alpha * hv.z; aw2 += alpha * hv.w;
  }
  float4 bb = *(const float4*)(b1 + l * 4);
  rowbuf[w][l * 4 + 0] = fmaxf(ax + bb.x, 0.f);
  rowbuf[w][l * 4 + 1] = fmaxf(ay + bb.y, 0.f);
  rowbuf[w][l * 4 + 2] = fmaxf(az + bb.z, 0.f);
  rowbuf[w][l * 4 + 3] = fmaxf(aw2 + bb.w, 0.f);
  asm volatile("s_waitcnt lgkmcnt(0)" ::: "memory");

  // h2[n,o] = sum_cc relu_row[cc] * W2[cc,o] : lane l -> o = l&15, grp = l>>4
  const int o = l & 15;
  const int grp = l >> 4;
  float a2 = 0.f;
#pragma unroll 8
  for (int t = 0; t < 64; ++t) {
    a2 += rowbuf[w][grp * 64 + t] * w2s[(grp * 64 + t) * 16 + o];
  }
  a2 += __shfl_xor(a2, 16);
  a2 += __shfl_xor(a2, 32);

  if (l < 16) {
    h2[(size_t)n * 16 + l] = a2;
    float ps = a2 * a_src2[l];
    float pd = a2 * a_dst2[l];
    ps += __shfl_xor(ps, 1); pd += __shfl_xor(pd, 1);
    ps += __shfl_xor(ps, 2); pd += __shfl_xor(pd, 2);
    ps += __shfl_xor(ps, 4); pd += __shfl_xor(pd, 4);
    ps += __shfl_xor(ps, 8); pd += __shfl_xor(pd, 8);
    if (l == 0) { als2[n] = ps; ald2[n] = pd; }
  }
}

// ============ GAT layer 2 aggregation -> x1, g, sortable keys ============
__global__ __launch_bounds__(256) void k_gat2(
    const float* __restrict__ h2, const float* __restrict__ als2,
    const float* __restrict__ ald2, const float* __restrict__ b2,
    const float* __restrict__ proj_w, const float* __restrict__ proj_b,
    const int* __restrict__ offsets, const int* __restrict__ csr_src,
    float* __restrict__ x1, float* __restrict__ g,
    unsigned long long* __restrict__ keys, int N) {
  const int w = threadIdx.x >> 6;
  const int l = threadIdx.x & 63;
  const int n = blockIdx.x * 4 + w;
  if (n >= N) return;
  const int off = offsets[n];
  const int deg = offsets[n + 1] - off;
  const float ad = ald2[n];

  float mx = -INFINITY;
  for (int e0 = 0; e0 < deg; e0 += 64) {
    int e = e0 + l;
    if (e < deg) {
      float v = leakyrelu02(als2[csr_src[off + e]] + ad);
      mx = fmaxf(mx, v);
    }
  }
#pragma unroll
  for (int d = 1; d < 64; d <<= 1) mx = fmaxf(mx, __shfl_xor(mx, d));

  float sm = 0.f;
  for (int e0 = 0; e0 < deg; e0 += 64) {
    int e = e0 + l;
    if (e < deg) {
      float v = leakyrelu02(als2[csr_src[off + e]] + ad);
      sm += expf(v - mx);
    }
  }
#pragma unroll
  for (int d = 1; d < 64; d <<= 1) sm += __shfl_xor(sm, d);
  const float inv = 1.f / (sm + 1e-16f);

  const int slot = l >> 4;
  const int c = l & 15;
  float acc = 0.f;
  for (int e0 = 0; e0 < deg; e0 += 4) {
    int e = e0 + slot;
    if (e < deg) {
      int s = csr_src[off + e];
      float v = leakyrelu02(als2[s] + ad);
      float alpha = expf(v - mx) * inv;
      acc += alpha * h2[(size_t)s * 16 + c];
    }
  }
  acc += __shfl_xor(acc, 16);
  acc += __shfl_xor(acc, 32);
  float x1v = acc + b2[c];
  float pg = (l < 16) ? x1v * proj_w[c] : 0.f;
#pragma unroll
  for (int d = 1; d < 64; d <<= 1) pg += __shfl_xor(pg, d);
  if (l < 16) x1[(size_t)n * 16 + l] = x1v;
  if (l == 0) {
    float gv = pg + proj_b[0];
    g[n] = gv;
    unsigned u = __float_as_uint(gv);
    u = (u & 0x80000000u) ? ~u : (u | 0x80000000u);
    keys[n] = (((unsigned long long)u) << 32) | (unsigned)n;
  }
}

// ============ brute-force exact stable rank (argsort) ============
// IPT=4 i-keys per thread: one LDS broadcast amortized over 4 u64 compares.
__global__ __launch_bounds__(256) void k_rank(const unsigned long long* __restrict__ keys,
                                              int* __restrict__ rank, int N, int jchunk) {
  __shared__ unsigned long long kt[1024];
  const int ibase = blockIdx.x * 1024 + threadIdx.x;
  unsigned long long ki[4];
#pragma unroll
  for (int k = 0; k < 4; ++k) {
    int i = ibase + k * 256;
    ki[k] = (i < N) ? keys[i] : ~0ull;
  }
  int r[4] = {0, 0, 0, 0};
  const int jbeg = blockIdx.y * jchunk;
  const int jend = min(N, jbeg + jchunk);
  for (int t0 = jbeg; t0 < jend; t0 += 1024) {
    int cnt = min(1024, jend - t0);
    __syncthreads();
    for (int t = threadIdx.x; t < cnt; t += 256) kt[t] = keys[t0 + t];
    __syncthreads();
    int t = 0;
    for (; t + 4 <= cnt; t += 4) {
      unsigned long long k0 = kt[t], k1 = kt[t + 1], k2 = kt[t + 2], k3 = kt[t + 3];
#pragma unroll
      for (int k = 0; k < 4; ++k) {
        r[k] += (int)(k0 < ki[k]) + (int)(k1 < ki[k]) + (int)(k2 < ki[k]) + (int)(k3 < ki[k]);
      }
    }
    for (; t < cnt; ++t) {
      unsigned long long kv = kt[t];
#pragma unroll
      for (int k = 0; k < 4; ++k) r[k] += (int)(kv < ki[k]);
    }
  }
#pragma unroll
  for (int k = 0; k < 4; ++k) {
    int i = ibase + k * 256;
    if (i < N) atomicAdd(&rank[i], r[k]);
  }
}

// ============ scatter g*x1 into sorted order ============
__global__ __launch_bounds__(256) void k_scatter_sorted(
    const float* __restrict__ g, const float* __restrict__ x1,
    const int* __restrict__ rank, float* __restrict__ sortedv, int N) {
  int n = blockIdx.x * 256 + threadIdx.x;
  if (n >= N) return;
  int r = rank[n];
  float gv = g[n];
#pragma unroll
  for (int c = 0; c < 16; c += 4) {
    float4 v = *(const float4*)(x1 + (size_t)n * 16 + c);
    float4 o = make_float4(gv * v.x, gv * v.y, gv * v.z, gv * v.w);
    *(float4*)(sortedv + (size_t)r * 16 + c) = o;
  }
}

// ============ conv1d 'same', K=5, 16->16 channels ============
__global__ __launch_bounds__(256) void k_conv(const float* __restrict__ in,
                                              const float* __restrict__ wgt,
                                              const float* __restrict__ bias,
                                              float* __restrict__ out, int N, int relu) {
  __shared__ float s[260][17];
  __shared__ float ws[1280];
  __shared__ float bs[16];
  const int p0 = blockIdx.x * 256;
  for (int i = threadIdx.x; i < 1280; i += 256) ws[i] = wgt[i];
  if (threadIdx.x < 16) bs[threadIdx.x] = bias[threadIdx.x];
  for (int idx = threadIdx.x; idx < 260 * 16; idx += 256) {
    int lp = idx >> 4, c = idx & 15;
    int gp = p0 - 2 + lp;
    s[lp][c] = (gp >= 0 && gp < N) ? in[(size_t)gp * 16 + c] : 0.f;
  }
  __syncthreads();
  const int p = p0 + threadIdx.x;
  if (p >= N) return;
  float acc[16];
#pragma unroll
  for (int o = 0; o < 16; ++o) acc[o] = bs[o];
  for (int k = 0; k < 5; ++k) {
    for (int c = 0; c < 16; ++c) {
      float xv = s[threadIdx.x + k][c];
#pragma unroll
      for (int o = 0; o < 16; ++o) acc[o] += ws[(o * 16 + c) * 5 + k] * xv;
    }
  }
#pragma unroll
  for (int o = 0; o < 16; ++o) {
    float v = acc[o];
    if (relu) v = fmaxf(v, 0.f);
    out[(size_t)p * 16 + o] = v;
  }
}

// ============ final: concat(x1, x2=conv2[rank]) @ lin_w + lin_b -> log_softmax ============
__global__ __launch_bounds__(256) void k_final(
    const float* __restrict__ x1, const float* __restrict__ c2out,
    const int* __restrict__ rank, const float* __restrict__ lin_w,
    const float* __restrict__ lin_b, float* __restrict__ out, int N) {
  __shared__ float lw[512];
  __shared__ float lb[16];
  for (int i = threadIdx.x; i < 512; i += 256) lw[i] = lin_w[i];
  if (threadIdx.x < 16) lb[threadIdx.x] = lin_b[threadIdx.x];
  __syncthreads();
  const int n = blockIdx.x * 256 + threadIdx.x;
  if (n >= N) return;
  float xa[16], xb[16];
  const int r = rank[n];
#pragma unroll
  for (int c = 0; c < 16; c += 4) {
    float4 va = *(const float4*)(x1 + (size_t)n * 16 + c);
    float4 vb = *(const float4*)(c2out + (size_t)r * 16 + c);
    xa[c] = va.x; xa[c + 1] = va.y; xa[c + 2] = va.z; xa[c + 3] = va.w;
    xb[c] = vb.x; xb[c + 1] = vb.y; xb[c + 2] = vb.z; xb[c + 3] = vb.w;
  }
  float z[16];
#pragma unroll
  for (int o = 0; o < 16; ++o) z[o] = lb[o];
#pragma unroll
  for (int c = 0; c < 16; ++c) {
    float va = xa[c], vb = xb[c];
#pragma unroll
    for (int o = 0; o < 16; ++o) z[o] += va * lw[c * 16 + o] + vb * lw[(16 + c) * 16 + o];
  }
  float m = z[0];
#pragma unroll
  for (int o = 1; o < 16; ++o) m = fmaxf(m, z[o]);
  float ssum = 0.f;
#pragma unroll
  for (int o = 0; o < 16; ++o) ssum += expf(z[o] - m);
  float lse = m + logf(ssum);
#pragma unroll
  for (int o = 0; o < 16; ++o) out[(size_t)n * 16 + o] = z[o] - lse;
}

extern "C" void kernel_launch(void* const* d_in, const int* in_sizes, int n_in,
                              void* d_out, int out_size, void* d_ws, size_t ws_size,
                              hipStream_t stream) {
  const float* x = (const float*)d_in[0];
  const int* ei = (const int*)d_in[1];
  const float* W1 = (const float*)d_in[2];
  const float* a_src1 = (const float*)d_in[3];
  const float* a_dst1 = (const float*)d_in[4];
  const float* b1 = (const float*)d_in[5];
  const float* W2 = (const float*)d_in[6];
  const float* a_src2 = (const float*)d_in[7];
  const float* a_dst2 = (const float*)d_in[8];
  const float* b2 = (const float*)d_in[9];
  const float* proj_w = (const float*)d_in[10];
  const float* proj_b = (const float*)d_in[11];
  const float* c1_w = (const float*)d_in[12];
  const float* c1_b = (const float*)d_in[13];
  const float* c2_w = (const float*)d_in[14];
  const float* c2_b = (const float*)d_in[15];
  const float* lin_w = (const float*)d_in[16];
  const float* lin_b = (const float*)d_in[17];
  float* out = (float*)d_out;

  const int N = in_sizes[0] / 256;
  const int E = in_sizes[1] / 2;
  const int Etot = E + N;

  char* ws = (char*)d_ws;
  size_t off = 0;
  auto alloc = [&](size_t bytes) -> void* {
    void* p = ws + off;
    off = (off + bytes + 255) & ~(size_t)255;
    return p;
  };
  float* h_lin = (float*)alloc((size_t)N * 256 * 4);
  float* als1 = (float*)alloc((size_t)N * 8 * 4);
  float* ald1 = (float*)alloc((size_t)N * 8 * 4);
  int* counts = (int*)alloc((size_t)N * 4);
  int* offsets = (int*)alloc((size_t)(N + 1) * 4);
  int* cursor = (int*)alloc((size_t)N * 4);
  int* csr_src = (int*)alloc((size_t)Etot * 4);
  float* h2 = (float*)alloc((size_t)N * 16 * 4);
  float* als2 = (float*)alloc((size_t)N * 4);
  float* ald2 = (float*)alloc((size_t)N * 4);
  float* x1 = (float*)alloc((size_t)N * 16 * 4);
  float* gbuf = (float*)alloc((size_t)N * 4);
  unsigned long long* keys = (unsigned long long*)alloc((size_t)N * 8);
  int* rank = (int*)alloc((size_t)N * 4);
  float* sortedv = (float*)alloc((size_t)N * 16 * 4);
  float* c1out = (float*)alloc((size_t)N * 16 * 4);
  float* c2out = (float*)alloc((size_t)N * 16 * 4);
  if (off > ws_size) return;  // fail loudly (poisoned output) rather than corrupt memory

  hipMemsetAsync(counts, 0, (size_t)N * 4, stream);
  hipMemsetAsync(rank, 0, (size_t)N * 4, stream);

  dim3 gg((N + 63) / 64, 4);
  k_gemm1<<<gg, 256, 0, stream>>>(x, W1, h_lin, N);
  k_al1<<<(N + 3) / 4, 256, 0, stream>>>(h_lin, a_src1, a_dst1, als1, ald1, N);
  k_hist<<<(Etot + 255) / 256, 256, 0, stream>>>(ei, counts, E, N);
  k_scan<<<1, 1024, 0, stream>>>(counts, offsets, cursor, N);
  k_scatter<<<(Etot + 255) / 256, 256, 0, stream>>>(ei, cursor, csr_src, E, N);
  k_gat1<<<(N + 3) / 4, 256, 0, stream>>>(h_lin, als1, ald1, b1, offsets, csr_src,
                                          W2, a_src2, a_dst2, h2, als2, ald2, N);
  k_gat2<<<(N + 3) / 4, 256, 0, stream>>>(h2, als2, ald2, b2, proj_w, proj_b,
                                          offsets, csr_src, x1, gbuf, keys, N);
  const int jsplit = 32;
  const int jchunk = (N + jsplit - 1) / jsplit;
  dim3 gr((N + 1023) / 1024, jsplit);
  k_rank<<<gr, 256, 0, stream>>>(keys, rank, N, jchunk);
  k_scatter_sorted<<<(N + 255) / 256, 256, 0, stream>>>(gbuf, x1, rank, sortedv, N);
  k_conv<<<(N + 255) / 256, 256, 0, stream>>>(sortedv, c1_w, c1_b, c1out, N, 1);
  k_conv<<<(N + 255) / 256, 256, 0, stream>>>(c1out, c2_w, c2_b, c2out, N, 0);
  k_final<<<(N + 255) / 256, 256, 0, stream>>>(x1, c2out, rank, lin_w, lin_b, out, N);
}

// Round 3
// 580.953 us; speedup vs baseline: 1.4481x; 1.3000x over previous
//
#include <hip/hip_runtime.h>
#include <math.h>

#define NBUCKET 65536

__device__ __forceinline__ float leakyrelu02(float v) { return v > 0.f ? v : 0.2f * v; }

// ============ GEMM: C[M,256] = A[M,256] @ B[256,256], fp32 ============
__global__ __launch_bounds__(256) void k_gemm1(const float* __restrict__ A,
                                               const float* __restrict__ B,
                                               float* __restrict__ C, int M) {
  __shared__ float As[16][68];
  __shared__ float Bs[16][64];
  const int m0 = blockIdx.x * 64;
  const int n0 = blockIdx.y * 64;
  const int tid = threadIdx.x;
  const int tm = tid & 15, tn = tid >> 4;
  float acc[4][4];
#pragma unroll
  for (int i = 0; i < 4; ++i)
#pragma unroll
    for (int j = 0; j < 4; ++j) acc[i][j] = 0.f;

  const int am = tid & 63, ak = (tid >> 6) << 2;
  const int bk = tid >> 4, bn = (tid & 15) << 2;

  for (int k0 = 0; k0 < 256; k0 += 16) {
    float4 av = make_float4(0.f, 0.f, 0.f, 0.f);
    if (m0 + am < M) av = *(const float4*)(A + (size_t)(m0 + am) * 256 + (k0 + ak));
    As[ak + 0][am] = av.x;
    As[ak + 1][am] = av.y;
    As[ak + 2][am] = av.z;
    As[ak + 3][am] = av.w;
    float4 bv = *(const float4*)(B + (size_t)(k0 + bk) * 256 + (n0 + bn));
    *(float4*)&Bs[bk][bn] = bv;
    __syncthreads();
#pragma unroll
    for (int kk = 0; kk < 16; ++kk) {
      float a[4], b[4];
#pragma unroll
      for (int i = 0; i < 4; ++i) a[i] = As[kk][tm * 4 + i];
#pragma unroll
      for (int j = 0; j < 4; ++j) b[j] = Bs[kk][tn * 4 + j];
#pragma unroll
      for (int i = 0; i < 4; ++i)
#pragma unroll
        for (int j = 0; j < 4; ++j) acc[i][j] += a[i] * b[j];
    }
    __syncthreads();
  }
#pragma unroll
  for (int i = 0; i < 4; ++i) {
    int m = m0 + tm * 4 + i;
    if (m < M) {
      float4 o = make_float4(acc[i][0], acc[i][1], acc[i][2], acc[i][3]);
      *(float4*)(C + (size_t)m * 256 + (n0 + tn * 4)) = o;
    }
  }
}

// ============ attention logits for layer 1: wave per node ============
__global__ __launch_bounds__(256) void k_al1(const float* __restrict__ h_lin,
                                             const float* __restrict__ a_src,
                                             const float* __restrict__ a_dst,
                                             float* __restrict__ als,
                                             float* __restrict__ ald, int N) {
  int gid = blockIdx.x * 256 + threadIdx.x;
  int n = gid >> 6;
  int l = threadIdx.x & 63;
  if (n >= N) return;
  float4 h4 = *(const float4*)(h_lin + (size_t)n * 256 + l * 4);
  float4 vs = *(const float4*)(a_src + l * 4);
  float4 vd = *(const float4*)(a_dst + l * 4);
  float ps = h4.x * vs.x + h4.y * vs.y + h4.z * vs.z + h4.w * vs.w;
  float pd = h4.x * vd.x + h4.y * vd.y + h4.z * vd.z + h4.w * vd.w;
  ps += __shfl_xor(ps, 1); pd += __shfl_xor(pd, 1);
  ps += __shfl_xor(ps, 2); pd += __shfl_xor(pd, 2);
  ps += __shfl_xor(ps, 4); pd += __shfl_xor(pd, 4);
  if ((l & 7) == 0) {
    als[(size_t)n * 8 + (l >> 3)] = ps;
    ald[(size_t)n * 8 + (l >> 3)] = pd;
  }
}

// ============ CSR build ============
__global__ __launch_bounds__(256) void k_hist(const int* __restrict__ ei,
                                              int* __restrict__ counts, int E, int N) {
  int e = blockIdx.x * 256 + threadIdx.x;
  if (e >= E + N) return;
  int d = (e < E) ? ei[E + e] : (e - E);
  atomicAdd(&counts[d], 1);
}

// scan over Npad = 1024*chunk entries (chunk multiple of 4, counts padded+zeroed)
__global__ __launch_bounds__(1024) void k_scan(const int* __restrict__ counts,
                                               int* __restrict__ offsets,
                                               int* __restrict__ cursor, int chunk) {
  __shared__ int part[1024];
  const int t = threadIdx.x;
  const int base = t * chunk;
  int ssum = 0;
  for (int i = 0; i < chunk; i += 4) {
    int4 v = *(const int4*)(counts + base + i);
    ssum += v.x + v.y + v.z + v.w;
  }
  part[t] = ssum;
  __syncthreads();
  for (int d = 1; d < 1024; d <<= 1) {
    int v = (t >= d) ? part[t - d] : 0;
    __syncthreads();
    part[t] += v;
    __syncthreads();
  }
  int run = (t == 0) ? 0 : part[t - 1];
  for (int i = 0; i < chunk; i += 4) {
    int4 v = *(const int4*)(counts + base + i);
    int4 o;
    o.x = run; run += v.x;
    o.y = run; run += v.y;
    o.z = run; run += v.z;
    o.w = run; run += v.w;
    *(int4*)(offsets + base + i) = o;
    if (cursor) *(int4*)(cursor + base + i) = o;
  }
  if (t == 1023) offsets[1024 * chunk] = run;
}

__global__ __launch_bounds__(256) void k_scatter(const int* __restrict__ ei,
                                                 int* __restrict__ cursor,
                                                 int* __restrict__ csr_src, int E, int N) {
  int e = blockIdx.x * 256 + threadIdx.x;
  if (e >= E + N) return;
  int d, s;
  if (e < E) { d = ei[E + e]; s = ei[e]; }
  else { d = e - E; s = e - E; }
  int pos = atomicAdd(&cursor[d], 1);
  csr_src[pos] = s;
}

// ============ GAT layer 1 aggregation + fused (relu row) @ W2 -> h2, al2 ============
__global__ __launch_bounds__(256) void k_gat1(
    const float* __restrict__ h_lin, const float* __restrict__ als1,
    const float* __restrict__ ald1, const float* __restrict__ b1,
    const int* __restrict__ offsets, const int* __restrict__ csr_src,
    const float* __restrict__ W2, const float* __restrict__ a_src2,
    const float* __restrict__ a_dst2, float* __restrict__ h2,
    float* __restrict__ als2, float* __restrict__ ald2, int N) {
  __shared__ float w2s[4096];
  __shared__ float rowbuf[4][256];
  for (int i = threadIdx.x; i < 4096; i += 256) w2s[i] = W2[i];
  __syncthreads();

  const int w = threadIdx.x >> 6;
  const int l = threadIdx.x & 63;
  const int n = blockIdx.x * 4 + w;
  if (n >= N) return;

  const int off = offsets[n];
  const int deg = offsets[n + 1] - off;

  const int h1 = l & 7;
  const int slot = l >> 3;
  const float adl = ald1[(size_t)n * 8 + h1];

  // pass 1: per-head max over incoming edges
  float mx = -INFINITY;
  for (int e0 = 0; e0 < deg; e0 += 8) {
    int e = e0 + slot;
    if (e < deg) {
      int s = csr_src[off + e];
      float v = leakyrelu02(als1[(size_t)s * 8 + h1] + adl);
      mx = fmaxf(mx, v);
    }
  }
  mx = fmaxf(mx, __shfl_xor(mx, 8));
  mx = fmaxf(mx, __shfl_xor(mx, 16));
  mx = fmaxf(mx, __shfl_xor(mx, 32));

  // pass 2: denominator
  float sm = 0.f;
  for (int e0 = 0; e0 < deg; e0 += 8) {
    int e = e0 + slot;
    if (e < deg) {
      int s = csr_src[off + e];
      float v = leakyrelu02(als1[(size_t)s * 8 + h1] + adl);
      sm += expf(v - mx);
    }
  }
  sm += __shfl_xor(sm, 8);
  sm += __shfl_xor(sm, 16);
  sm += __shfl_xor(sm, 32);
  const float inv = 1.f / (sm + 1e-16f);

  // rearrange per-head stats: lane's channels l*4.. belong to head l>>3
  const int h3 = l >> 3;
  const float mh = __shfl(mx, h3);
  const float ih = __shfl(inv, h3);
  const float ad3 = __shfl(adl, h3);

  // pass 3: weighted aggregation of h_lin[src]
  float ax = 0.f, ay = 0.f, az = 0.f, aw2 = 0.f;
  for (int e = 0; e < deg; ++e) {
    int s = csr_src[off + e];
    float v = leakyrelu02(als1[(size_t)s * 8 + h3] + ad3);
    float alpha = expf(v - mh) * ih;
    float4 hv = *(const float4*)(h_lin + (size_t)s * 256 + l * 4);
    ax += alpha * hv.x; ay += alpha * hv.y; az += alpha * hv.z; aw2 += alpha * hv.w;
  }
  float4 bb = *(const float4*)(b1 + l * 4);
  rowbuf[w][l * 4 + 0] = fmaxf(ax + bb.x, 0.f);
  rowbuf[w][l * 4 + 1] = fmaxf(ay + bb.y, 0.f);
  rowbuf[w][l * 4 + 2] = fmaxf(az + bb.z, 0.f);
  rowbuf[w][l * 4 + 3] = fmaxf(aw2 + bb.w, 0.f);
  asm volatile("s_waitcnt lgkmcnt(0)" ::: "memory");

  // h2[n,o] = sum_cc relu_row[cc] * W2[cc,o] : lane l -> o = l&15, grp = l>>4
  const int o = l & 15;
  const int grp = l >> 4;
  float a2 = 0.f;
#pragma unroll 8
  for (int t = 0; t < 64; ++t) {
    a2 += rowbuf[w][grp * 64 + t] * w2s[(grp * 64 + t) * 16 + o];
  }
  a2 += __shfl_xor(a2, 16);
  a2 += __shfl_xor(a2, 32);

  if (l < 16) {
    h2[(size_t)n * 16 + l] = a2;
    float ps = a2 * a_src2[l];
    float pd = a2 * a_dst2[l];
    ps += __shfl_xor(ps, 1); pd += __shfl_xor(pd, 1);
    ps += __shfl_xor(ps, 2); pd += __shfl_xor(pd, 2);
    ps += __shfl_xor(ps, 4); pd += __shfl_xor(pd, 4);
    ps += __shfl_xor(ps, 8); pd += __shfl_xor(pd, 8);
    if (l == 0) { als2[n] = ps; ald2[n] = pd; }
  }
}

// ============ GAT layer 2 aggregation -> x1, g, sortable keys + bucket hist ============
__global__ __launch_bounds__(256) void k_gat2(
    const float* __restrict__ h2, const float* __restrict__ als2,
    const float* __restrict__ ald2, const float* __restrict__ b2,
    const float* __restrict__ proj_w, const float* __restrict__ proj_b,
    const int* __restrict__ offsets, const int* __restrict__ csr_src,
    float* __restrict__ x1, float* __restrict__ g,
    unsigned long long* __restrict__ keys, int* __restrict__ bhist, int N) {
  const int w = threadIdx.x >> 6;
  const int l = threadIdx.x & 63;
  const int n = blockIdx.x * 4 + w;
  if (n >= N) return;
  const int off = offsets[n];
  const int deg = offsets[n + 1] - off;
  const float ad = ald2[n];

  float mx = -INFINITY;
  for (int e0 = 0; e0 < deg; e0 += 64) {
    int e = e0 + l;
    if (e < deg) {
      float v = leakyrelu02(als2[csr_src[off + e]] + ad);
      mx = fmaxf(mx, v);
    }
  }
#pragma unroll
  for (int d = 1; d < 64; d <<= 1) mx = fmaxf(mx, __shfl_xor(mx, d));

  float sm = 0.f;
  for (int e0 = 0; e0 < deg; e0 += 64) {
    int e = e0 + l;
    if (e < deg) {
      float v = leakyrelu02(als2[csr_src[off + e]] + ad);
      sm += expf(v - mx);
    }
  }
#pragma unroll
  for (int d = 1; d < 64; d <<= 1) sm += __shfl_xor(sm, d);
  const float inv = 1.f / (sm + 1e-16f);

  const int slot = l >> 4;
  const int c = l & 15;
  float acc = 0.f;
  for (int e0 = 0; e0 < deg; e0 += 4) {
    int e = e0 + slot;
    if (e < deg) {
      int s = csr_src[off + e];
      float v = leakyrelu02(als2[s] + ad);
      float alpha = expf(v - mx) * inv;
      acc += alpha * h2[(size_t)s * 16 + c];
    }
  }
  acc += __shfl_xor(acc, 16);
  acc += __shfl_xor(acc, 32);
  float x1v = acc + b2[c];
  float pg = (l < 16) ? x1v * proj_w[c] : 0.f;
#pragma unroll
  for (int d = 1; d < 64; d <<= 1) pg += __shfl_xor(pg, d);
  if (l < 16) x1[(size_t)n * 16 + l] = x1v;
  if (l == 0) {
    float gv = pg + proj_b[0];
    g[n] = gv;
    unsigned u = __float_as_uint(gv);
    u = (u & 0x80000000u) ? ~u : (u | 0x80000000u);
    keys[n] = (((unsigned long long)u) << 32) | (unsigned)n;
    atomicAdd(&bhist[u >> 16], 1);
  }
}

// ============ bucket scatter: place key64 into its bucket (order within bucket arbitrary) ============
__global__ __launch_bounds__(256) void k_bscatter(const unsigned long long* __restrict__ keys,
                                                  int* __restrict__ cursor,
                                                  unsigned long long* __restrict__ bkeys, int N) {
  int n = blockIdx.x * 256 + threadIdx.x;
  if (n >= N) return;
  unsigned long long k = keys[n];
  int b = (int)(k >> 48);
  int pos = atomicAdd(&cursor[b], 1);
  bkeys[pos] = k;
}

// ============ exact stable rank within bucket + scatter g*x1 to sorted order ============
__global__ __launch_bounds__(256) void k_brank(const unsigned long long* __restrict__ bkeys,
                                               const int* __restrict__ boffs,
                                               const float* __restrict__ g,
                                               const float* __restrict__ x1,
                                               int* __restrict__ rank,
                                               float* __restrict__ sortedv, int N) {
  int pos = blockIdx.x * 256 + threadIdx.x;
  if (pos >= N) return;
  unsigned long long k = bkeys[pos];
  int b = (int)(k >> 48);
  int lo = boffs[b], hi = boffs[b + 1];
  int r = lo;
  for (int j = lo; j < hi; ++j) r += (bkeys[j] < k) ? 1 : 0;
  int idx = (int)(unsigned)(k & 0xffffffffull);
  rank[idx] = r;
  float gv = g[idx];
#pragma unroll
  for (int c = 0; c < 16; c += 4) {
    float4 v = *(const float4*)(x1 + (size_t)idx * 16 + c);
    float4 o = make_float4(gv * v.x, gv * v.y, gv * v.z, gv * v.w);
    *(float4*)(sortedv + (size_t)r * 16 + c) = o;
  }
}

// ============ conv1d 'same', K=5, 16->16 channels ============
__global__ __launch_bounds__(256) void k_conv(const float* __restrict__ in,
                                              const float* __restrict__ wgt,
                                              const float* __restrict__ bias,
                                              float* __restrict__ out, int N, int relu) {
  __shared__ float s[260][17];
  __shared__ float ws[1280];
  __shared__ float bs[16];
  const int p0 = blockIdx.x * 256;
  for (int i = threadIdx.x; i < 1280; i += 256) ws[i] = wgt[i];
  if (threadIdx.x < 16) bs[threadIdx.x] = bias[threadIdx.x];
  for (int idx = threadIdx.x; idx < 260 * 16; idx += 256) {
    int lp = idx >> 4, c = idx & 15;
    int gp = p0 - 2 + lp;
    s[lp][c] = (gp >= 0 && gp < N) ? in[(size_t)gp * 16 + c] : 0.f;
  }
  __syncthreads();
  const int p = p0 + threadIdx.x;
  if (p >= N) return;
  float acc[16];
#pragma unroll
  for (int o = 0; o < 16; ++o) acc[o] = bs[o];
  for (int k = 0; k < 5; ++k) {
    for (int c = 0; c < 16; ++c) {
      float xv = s[threadIdx.x + k][c];
#pragma unroll
      for (int o = 0; o < 16; ++o) acc[o] += ws[(o * 16 + c) * 5 + k] * xv;
    }
  }
#pragma unroll
  for (int o = 0; o < 16; ++o) {
    float v = acc[o];
    if (relu) v = fmaxf(v, 0.f);
    out[(size_t)p * 16 + o] = v;
  }
}

// ============ final: concat(x1, x2=conv2[rank]) @ lin_w + lin_b -> log_softmax ============
__global__ __launch_bounds__(256) void k_final(
    const float* __restrict__ x1, const float* __restrict__ c2out,
    const int* __restrict__ rank, const float* __restrict__ lin_w,
    const float* __restrict__ lin_b, float* __restrict__ out, int N) {
  __shared__ float lw[512];
  __shared__ float lb[16];
  for (int i = threadIdx.x; i < 512; i += 256) lw[i] = lin_w[i];
  if (threadIdx.x < 16) lb[threadIdx.x] = lin_b[threadIdx.x];
  __syncthreads();
  const int n = blockIdx.x * 256 + threadIdx.x;
  if (n >= N) return;
  float xa[16], xb[16];
  const int r = rank[n];
#pragma unroll
  for (int c = 0; c < 16; c += 4) {
    float4 va = *(const float4*)(x1 + (size_t)n * 16 + c);
    float4 vb = *(const float4*)(c2out + (size_t)r * 16 + c);
    xa[c] = va.x; xa[c + 1] = va.y; xa[c + 2] = va.z; xa[c + 3] = va.w;
    xb[c] = vb.x; xb[c + 1] = vb.y; xb[c + 2] = vb.z; xb[c + 3] = vb.w;
  }
  float z[16];
#pragma unroll
  for (int o = 0; o < 16; ++o) z[o] = lb[o];
#pragma unroll
  for (int c = 0; c < 16; ++c) {
    float va = xa[c], vb = xb[c];
#pragma unroll
    for (int o = 0; o < 16; ++o) z[o] += va * lw[c * 16 + o] + vb * lw[(16 + c) * 16 + o];
  }
  float m = z[0];
#pragma unroll
  for (int o = 1; o < 16; ++o) m = fmaxf(m, z[o]);
  float ssum = 0.f;
#pragma unroll
  for (int o = 0; o < 16; ++o) ssum += expf(z[o] - m);
  float lse = m + logf(ssum);
#pragma unroll
  for (int o = 0; o < 16; ++o) out[(size_t)n * 16 + o] = z[o] - lse;
}

extern "C" void kernel_launch(void* const* d_in, const int* in_sizes, int n_in,
                              void* d_out, int out_size, void* d_ws, size_t ws_size,
                              hipStream_t stream) {
  const float* x = (const float*)d_in[0];
  const int* ei = (const int*)d_in[1];
  const float* W1 = (const float*)d_in[2];
  const float* a_src1 = (const float*)d_in[3];
  const float* a_dst1 = (const float*)d_in[4];
  const float* b1 = (const float*)d_in[5];
  const float* W2 = (const float*)d_in[6];
  const float* a_src2 = (const float*)d_in[7];
  const float* a_dst2 = (const float*)d_in[8];
  const float* b2 = (const float*)d_in[9];
  const float* proj_w = (const float*)d_in[10];
  const float* proj_b = (const float*)d_in[11];
  const float* c1_w = (const float*)d_in[12];
  const float* c1_b = (const float*)d_in[13];
  const float* c2_w = (const float*)d_in[14];
  const float* c2_b = (const float*)d_in[15];
  const float* lin_w = (const float*)d_in[16];
  const float* lin_b = (const float*)d_in[17];
  float* out = (float*)d_out;

  const int N = in_sizes[0] / 256;
  const int E = in_sizes[1] / 2;
  const int Etot = E + N;

  // CSR scan padding: 1024 threads x chunk, chunk multiple of 4
  int chunk = (N + 1023) / 1024;
  chunk = (chunk + 3) & ~3;
  const int Npad = 1024 * chunk;

  char* ws = (char*)d_ws;
  size_t off = 0;
  auto alloc = [&](size_t bytes) -> void* {
    void* p = ws + off;
    off = (off + bytes + 255) & ~(size_t)255;
    return p;
  };
  float* h_lin = (float*)alloc((size_t)N * 256 * 4);
  float* als1 = (float*)alloc((size_t)N * 8 * 4);
  float* ald1 = (float*)alloc((size_t)N * 8 * 4);
  int* counts = (int*)alloc((size_t)Npad * 4);
  int* offsets = (int*)alloc((size_t)(Npad + 1) * 4);
  int* cursor = (int*)alloc((size_t)Npad * 4);
  int* csr_src = (int*)alloc((size_t)Etot * 4);
  float* h2 = (float*)alloc((size_t)N * 16 * 4);
  float* als2 = (float*)alloc((size_t)N * 4);
  float* ald2 = (float*)alloc((size_t)N * 4);
  float* x1 = (float*)alloc((size_t)N * 16 * 4);
  float* gbuf = (float*)alloc((size_t)N * 4);
  unsigned long long* keys = (unsigned long long*)alloc((size_t)N * 8);
  int* bhist = (int*)alloc((size_t)NBUCKET * 4);
  int* boffs = (int*)alloc((size_t)(NBUCKET + 1) * 4);
  int* bcursor = (int*)alloc((size_t)NBUCKET * 4);
  unsigned long long* bkeys = (unsigned long long*)alloc((size_t)N * 8);
  int* rank = (int*)alloc((size_t)N * 4);
  float* sortedv = (float*)alloc((size_t)N * 16 * 4);
  float* c1out = (float*)alloc((size_t)N * 16 * 4);
  float* c2out = (float*)alloc((size_t)N * 16 * 4);
  if (off > ws_size) return;  // fail loudly (poisoned output) rather than corrupt memory

  hipMemsetAsync(counts, 0, (size_t)Npad * 4, stream);
  hipMemsetAsync(bhist, 0, (size_t)NBUCKET * 4, stream);

  dim3 gg((N + 63) / 64, 4);
  k_gemm1<<<gg, 256, 0, stream>>>(x, W1, h_lin, N);
  k_al1<<<(N + 3) / 4, 256, 0, stream>>>(h_lin, a_src1, a_dst1, als1, ald1, N);
  k_hist<<<(Etot + 255) / 256, 256, 0, stream>>>(ei, counts, E, N);
  k_scan<<<1, 1024, 0, stream>>>(counts, offsets, cursor, chunk);
  k_scatter<<<(Etot + 255) / 256, 256, 0, stream>>>(ei, cursor, csr_src, E, N);
  k_gat1<<<(N + 3) / 4, 256, 0, stream>>>(h_lin, als1, ald1, b1, offsets, csr_src,
                                          W2, a_src2, a_dst2, h2, als2, ald2, N);
  k_gat2<<<(N + 3) / 4, 256, 0, stream>>>(h2, als2, ald2, b2, proj_w, proj_b,
                                          offsets, csr_src, x1, gbuf, keys, bhist, N);
  k_scan<<<1, 1024, 0, stream>>>(bhist, boffs, bcursor, NBUCKET / 1024);
  k_bscatter<<<(N + 255) / 256, 256, 0, stream>>>(keys, bcursor, bkeys, N);
  k_brank<<<(N + 255) / 256, 256, 0, stream>>>(bkeys, boffs, gbuf, x1, rank, sortedv, N);
  k_conv<<<(N + 255) / 256, 256, 0, stream>>>(sortedv, c1_w, c1_b, c1out, N, 1);
  k_conv<<<(N + 255) / 256, 256, 0, stream>>>(c1out, c2_w, c2_b, c2out, N, 0);
  k_final<<<(N + 255) / 256, 256, 0, stream>>>(x1, c2out, rank, lin_w, lin_b, out, N);
}

// Round 4
// 537.221 us; speedup vs baseline: 1.5660x; 1.0814x over previous
//
#include <hip/hip_runtime.h>
#include <math.h>

#define NBUCKET 65536

__device__ __forceinline__ float leakyrelu02(float v) { return v > 0.f ? v : 0.2f * v; }

// ============ GEMM: C[M,256] = A[M,256] @ B[256,256], fp32 ============
__global__ __launch_bounds__(256) void k_gemm1(const float* __restrict__ A,
                                               const float* __restrict__ B,
                                               float* __restrict__ C, int M) {
  __shared__ float As[16][68];
  __shared__ float Bs[16][64];
  const int m0 = blockIdx.x * 64;
  const int n0 = blockIdx.y * 64;
  const int tid = threadIdx.x;
  const int tm = tid & 15, tn = tid >> 4;
  float acc[4][4];
#pragma unroll
  for (int i = 0; i < 4; ++i)
#pragma unroll
    for (int j = 0; j < 4; ++j) acc[i][j] = 0.f;

  const int am = tid & 63, ak = (tid >> 6) << 2;
  const int bk = tid >> 4, bn = (tid & 15) << 2;

  for (int k0 = 0; k0 < 256; k0 += 16) {
    float4 av = make_float4(0.f, 0.f, 0.f, 0.f);
    if (m0 + am < M) av = *(const float4*)(A + (size_t)(m0 + am) * 256 + (k0 + ak));
    As[ak + 0][am] = av.x;
    As[ak + 1][am] = av.y;
    As[ak + 2][am] = av.z;
    As[ak + 3][am] = av.w;
    float4 bv = *(const float4*)(B + (size_t)(k0 + bk) * 256 + (n0 + bn));
    *(float4*)&Bs[bk][bn] = bv;
    __syncthreads();
#pragma unroll
    for (int kk = 0; kk < 16; ++kk) {
      float a[4], b[4];
#pragma unroll
      for (int i = 0; i < 4; ++i) a[i] = As[kk][tm * 4 + i];
#pragma unroll
      for (int j = 0; j < 4; ++j) b[j] = Bs[kk][tn * 4 + j];
#pragma unroll
      for (int i = 0; i < 4; ++i)
#pragma unroll
        for (int j = 0; j < 4; ++j) acc[i][j] += a[i] * b[j];
    }
    __syncthreads();
  }
#pragma unroll
  for (int i = 0; i < 4; ++i) {
    int m = m0 + tm * 4 + i;
    if (m < M) {
      float4 o = make_float4(acc[i][0], acc[i][1], acc[i][2], acc[i][3]);
      *(float4*)(C + (size_t)m * 256 + (n0 + tn * 4)) = o;
    }
  }
}

// ============ attention logits for layer 1: wave per node ============
__global__ __launch_bounds__(256) void k_al1(const float* __restrict__ h_lin,
                                             const float* __restrict__ a_src,
                                             const float* __restrict__ a_dst,
                                             float* __restrict__ als,
                                             float* __restrict__ ald, int N) {
  int gid = blockIdx.x * 256 + threadIdx.x;
  int n = gid >> 6;
  int l = threadIdx.x & 63;
  if (n >= N) return;
  float4 h4 = *(const float4*)(h_lin + (size_t)n * 256 + l * 4);
  float4 vs = *(const float4*)(a_src + l * 4);
  float4 vd = *(const float4*)(a_dst + l * 4);
  float ps = h4.x * vs.x + h4.y * vs.y + h4.z * vs.z + h4.w * vs.w;
  float pd = h4.x * vd.x + h4.y * vd.y + h4.z * vd.z + h4.w * vd.w;
  ps += __shfl_xor(ps, 1); pd += __shfl_xor(pd, 1);
  ps += __shfl_xor(ps, 2); pd += __shfl_xor(pd, 2);
  ps += __shfl_xor(ps, 4); pd += __shfl_xor(pd, 4);
  if ((l & 7) == 0) {
    als[(size_t)n * 8 + (l >> 3)] = ps;
    ald[(size_t)n * 8 + (l >> 3)] = pd;
  }
}

// ============ CSR build ============
__global__ __launch_bounds__(256) void k_hist(const int* __restrict__ ei,
                                              int* __restrict__ counts, int E, int N) {
  int e = blockIdx.x * 256 + threadIdx.x;
  if (e >= E + N) return;
  int d = (e < E) ? ei[E + e] : (e - E);
  atomicAdd(&counts[d], 1);
}

// scan over Npad = 1024*chunk entries (chunk multiple of 4, counts padded+zeroed)
__global__ __launch_bounds__(1024) void k_scan(const int* __restrict__ counts,
                                               int* __restrict__ offsets,
                                               int* __restrict__ cursor, int chunk) {
  __shared__ int part[1024];
  const int t = threadIdx.x;
  const int base = t * chunk;
  int ssum = 0;
  for (int i = 0; i < chunk; i += 4) {
    int4 v = *(const int4*)(counts + base + i);
    ssum += v.x + v.y + v.z + v.w;
  }
  part[t] = ssum;
  __syncthreads();
  for (int d = 1; d < 1024; d <<= 1) {
    int v = (t >= d) ? part[t - d] : 0;
    __syncthreads();
    part[t] += v;
    __syncthreads();
  }
  int run = (t == 0) ? 0 : part[t - 1];
  for (int i = 0; i < chunk; i += 4) {
    int4 v = *(const int4*)(counts + base + i);
    int4 o;
    o.x = run; run += v.x;
    o.y = run; run += v.y;
    o.z = run; run += v.z;
    o.w = run; run += v.w;
    *(int4*)(offsets + base + i) = o;
    if (cursor) *(int4*)(cursor + base + i) = o;
  }
  if (t == 1023) offsets[1024 * chunk] = run;
}

__global__ __launch_bounds__(256) void k_scatter(const int* __restrict__ ei,
                                                 int* __restrict__ cursor,
                                                 int* __restrict__ csr_src, int E, int N) {
  int e = blockIdx.x * 256 + threadIdx.x;
  if (e >= E + N) return;
  int d, s;
  if (e < E) { d = ei[E + e]; s = ei[e]; }
  else { d = e - E; s = e - E; }
  int pos = atomicAdd(&cursor[d], 1);
  csr_src[pos] = s;
}

// ============ GAT layer 1: single-pass aggregation (no max-subtraction; exact up to
// fp rounding since softmax is shift-invariant and logits are bounded ~|8|) +
// fused (relu row) @ W2 -> h2, al2 ============
__global__ __launch_bounds__(256) void k_gat1(
    const float* __restrict__ h_lin, const float* __restrict__ als1,
    const float* __restrict__ ald1, const float* __restrict__ b1,
    const int* __restrict__ offsets, const int* __restrict__ csr_src,
    const float* __restrict__ W2, const float* __restrict__ a_src2,
    const float* __restrict__ a_dst2, float* __restrict__ h2,
    float* __restrict__ als2, float* __restrict__ ald2, int N) {
  __shared__ float w2s[4352];          // [cc]*17 + o  (stride 17 kills 4-way conflicts)
  __shared__ float rowbuf[4][256];
  for (int i = threadIdx.x; i < 4096; i += 256) w2s[(i >> 4) * 17 + (i & 15)] = W2[i];
  __syncthreads();

  const int w = threadIdx.x >> 6;
  const int l = threadIdx.x & 63;
  const int n = blockIdx.x * 4 + w;
  if (n >= N) return;

  const int off = offsets[n];
  const int deg = offsets[n + 1] - off;

  const int h3 = l >> 3;  // head owning this lane's 4 channels
  const float ad3 = ald1[(size_t)n * 8 + h3];
  const float* hb = h_lin + l * 4;

  // single pass: acc = sum exp(v)*h[src], sw = sum exp(v); 4-way unrolled for MLP
  float ax = 0.f, ay = 0.f, az = 0.f, aw2 = 0.f, sw = 0.f;
  int e = 0;
  for (; e + 4 <= deg; e += 4) {
    int s0 = csr_src[off + e + 0];
    int s1 = csr_src[off + e + 1];
    int s2 = csr_src[off + e + 2];
    int s3 = csr_src[off + e + 3];
    float v0 = als1[(size_t)s0 * 8 + h3];
    float v1 = als1[(size_t)s1 * 8 + h3];
    float v2 = als1[(size_t)s2 * 8 + h3];
    float v3 = als1[(size_t)s3 * 8 + h3];
    float4 r0 = *(const float4*)(hb + (size_t)s0 * 256);
    float4 r1 = *(const float4*)(hb + (size_t)s1 * 256);
    float4 r2 = *(const float4*)(hb + (size_t)s2 * 256);
    float4 r3 = *(const float4*)(hb + (size_t)s3 * 256);
    float w0 = expf(leakyrelu02(v0 + ad3));
    float w1 = expf(leakyrelu02(v1 + ad3));
    float w2v = expf(leakyrelu02(v2 + ad3));
    float w3 = expf(leakyrelu02(v3 + ad3));
    sw += (w0 + w1) + (w2v + w3);
    ax += w0 * r0.x + w1 * r1.x + w2v * r2.x + w3 * r3.x;
    ay += w0 * r0.y + w1 * r1.y + w2v * r2.y + w3 * r3.y;
    az += w0 * r0.z + w1 * r1.z + w2v * r2.z + w3 * r3.z;
    aw2 += w0 * r0.w + w1 * r1.w + w2v * r2.w + w3 * r3.w;
  }
  for (; e < deg; ++e) {
    int s = csr_src[off + e];
    float ww = expf(leakyrelu02(als1[(size_t)s * 8 + h3] + ad3));
    float4 r = *(const float4*)(hb + (size_t)s * 256);
    sw += ww;
    ax += ww * r.x; ay += ww * r.y; az += ww * r.z; aw2 += ww * r.w;
  }
  const float inv = 1.f / (sw + 1e-16f);

  float4 bb = *(const float4*)(b1 + l * 4);
  rowbuf[w][l * 4 + 0] = fmaxf(ax * inv + bb.x, 0.f);
  rowbuf[w][l * 4 + 1] = fmaxf(ay * inv + bb.y, 0.f);
  rowbuf[w][l * 4 + 2] = fmaxf(az * inv + bb.z, 0.f);
  rowbuf[w][l * 4 + 3] = fmaxf(aw2 * inv + bb.w, 0.f);
  asm volatile("s_waitcnt lgkmcnt(0)" ::: "memory");

  // h2[n,o] = sum_cc relu_row[cc] * W2[cc,o]; grp-rotated walk -> banks 17t+8grp+o (2-way max)
  const int o = l & 15;
  const int grp = l >> 4;
  float a2 = 0.f;
#pragma unroll 8
  for (int t = 0; t < 64; ++t) {
    int cc = grp * 64 + ((t + grp * 8) & 63);
    a2 += rowbuf[w][cc] * w2s[cc * 17 + o];
  }
  a2 += __shfl_xor(a2, 16);
  a2 += __shfl_xor(a2, 32);

  if (l < 16) {
    h2[(size_t)n * 16 + l] = a2;
    float ps = a2 * a_src2[l];
    float pd = a2 * a_dst2[l];
    ps += __shfl_xor(ps, 1); pd += __shfl_xor(pd, 1);
    ps += __shfl_xor(ps, 2); pd += __shfl_xor(pd, 2);
    ps += __shfl_xor(ps, 4); pd += __shfl_xor(pd, 4);
    ps += __shfl_xor(ps, 8); pd += __shfl_xor(pd, 8);
    if (l == 0) { als2[n] = ps; ald2[n] = pd; }
  }
}

// ============ GAT layer 2: single-pass aggregation -> x1, g, keys + bucket hist ============
__global__ __launch_bounds__(256) void k_gat2(
    const float* __restrict__ h2, const float* __restrict__ als2,
    const float* __restrict__ ald2, const float* __restrict__ b2,
    const float* __restrict__ proj_w, const float* __restrict__ proj_b,
    const int* __restrict__ offsets, const int* __restrict__ csr_src,
    float* __restrict__ x1, float* __restrict__ g,
    unsigned long long* __restrict__ keys, int* __restrict__ bhist, int N) {
  const int w = threadIdx.x >> 6;
  const int l = threadIdx.x & 63;
  const int n = blockIdx.x * 4 + w;
  if (n >= N) return;
  const int off = offsets[n];
  const int deg = offsets[n + 1] - off;
  const float ad = ald2[n];
  const int slot = l >> 4;  // 4 parallel edge slots
  const int c = l & 15;

  float acc = 0.f, sw = 0.f;
  int e0 = 0;
  for (; e0 + 8 <= deg; e0 += 8) {
    int sA = csr_src[off + e0 + slot];
    int sB = csr_src[off + e0 + 4 + slot];
    float vA = als2[sA];
    float vB = als2[sB];
    float hA = h2[(size_t)sA * 16 + c];
    float hB = h2[(size_t)sB * 16 + c];
    float wA = expf(leakyrelu02(vA + ad));
    float wB = expf(leakyrelu02(vB + ad));
    sw += wA + wB;
    acc += wA * hA + wB * hB;
  }
  for (; e0 < deg; e0 += 4) {
    int e = e0 + slot;
    if (e < deg) {
      int s = csr_src[off + e];
      float v = expf(leakyrelu02(als2[s] + ad));
      sw += v;
      acc += v * h2[(size_t)s * 16 + c];
    }
  }
  acc += __shfl_xor(acc, 16); sw += __shfl_xor(sw, 16);
  acc += __shfl_xor(acc, 32); sw += __shfl_xor(sw, 32);
  float x1v = acc / (sw + 1e-16f) + b2[c];

  float pg = x1v * proj_w[c];
  pg += __shfl_xor(pg, 1);
  pg += __shfl_xor(pg, 2);
  pg += __shfl_xor(pg, 4);
  pg += __shfl_xor(pg, 8);
  if (l < 16) x1[(size_t)n * 16 + l] = x1v;
  if (l == 0) {
    float gv = pg + proj_b[0];
    g[n] = gv;
    unsigned u = __float_as_uint(gv);
    u = (u & 0x80000000u) ? ~u : (u | 0x80000000u);
    keys[n] = (((unsigned long long)u) << 32) | (unsigned)n;
    atomicAdd(&bhist[u >> 16], 1);
  }
}

// ============ bucket scatter: place key64 into its bucket (order within bucket arbitrary) ============
__global__ __launch_bounds__(256) void k_bscatter(const unsigned long long* __restrict__ keys,
                                                  int* __restrict__ cursor,
                                                  unsigned long long* __restrict__ bkeys, int N) {
  int n = blockIdx.x * 256 + threadIdx.x;
  if (n >= N) return;
  unsigned long long k = keys[n];
  int b = (int)(k >> 48);
  int pos = atomicAdd(&cursor[b], 1);
  bkeys[pos] = k;
}

// ============ exact stable rank within bucket + scatter g*x1 to sorted order ============
__global__ __launch_bounds__(256) void k_brank(const unsigned long long* __restrict__ bkeys,
                                               const int* __restrict__ boffs,
                                               const float* __restrict__ g,
                                               const float* __restrict__ x1,
                                               int* __restrict__ rank,
                                               float* __restrict__ sortedv, int N) {
  int pos = blockIdx.x * 256 + threadIdx.x;
  if (pos >= N) return;
  unsigned long long k = bkeys[pos];
  int b = (int)(k >> 48);
  int lo = boffs[b], hi = boffs[b + 1];
  int r = lo;
  for (int j = lo; j < hi; ++j) r += (bkeys[j] < k) ? 1 : 0;
  int idx = (int)(unsigned)(k & 0xffffffffull);
  rank[idx] = r;
  float gv = g[idx];
#pragma unroll
  for (int c = 0; c < 16; c += 4) {
    float4 v = *(const float4*)(x1 + (size_t)idx * 16 + c);
    float4 o = make_float4(gv * v.x, gv * v.y, gv * v.z, gv * v.w);
    *(float4*)(sortedv + (size_t)r * 16 + c) = o;
  }
}

// ============ conv1d 'same', K=5, 16->16 channels ============
__global__ __launch_bounds__(256) void k_conv(const float* __restrict__ in,
                                              const float* __restrict__ wgt,
                                              const float* __restrict__ bias,
                                              float* __restrict__ out, int N, int relu) {
  __shared__ float s[260][17];
  __shared__ float ws[1280];
  __shared__ float bs[16];
  const int p0 = blockIdx.x * 256;
  for (int i = threadIdx.x; i < 1280; i += 256) ws[i] = wgt[i];
  if (threadIdx.x < 16) bs[threadIdx.x] = bias[threadIdx.x];
  for (int idx = threadIdx.x; idx < 260 * 16; idx += 256) {
    int lp = idx >> 4, c = idx & 15;
    int gp = p0 - 2 + lp;
    s[lp][c] = (gp >= 0 && gp < N) ? in[(size_t)gp * 16 + c] : 0.f;
  }
  __syncthreads();
  const int p = p0 + threadIdx.x;
  if (p >= N) return;
  float acc[16];
#pragma unroll
  for (int o = 0; o < 16; ++o) acc[o] = bs[o];
  for (int k = 0; k < 5; ++k) {
    for (int c = 0; c < 16; ++c) {
      float xv = s[threadIdx.x + k][c];
#pragma unroll
      for (int o = 0; o < 16; ++o) acc[o] += ws[(o * 16 + c) * 5 + k] * xv;
    }
  }
#pragma unroll
  for (int o = 0; o < 16; ++o) {
    float v = acc[o];
    if (relu) v = fmaxf(v, 0.f);
    out[(size_t)p * 16 + o] = v;
  }
}

// ============ final: concat(x1, x2=conv2[rank]) @ lin_w + lin_b -> log_softmax ============
__global__ __launch_bounds__(256) void k_final(
    const float* __restrict__ x1, const float* __restrict__ c2out,
    const int* __restrict__ rank, const float* __restrict__ lin_w,
    const float* __restrict__ lin_b, float* __restrict__ out, int N) {
  __shared__ float lw[512];
  __shared__ float lb[16];
  for (int i = threadIdx.x; i < 512; i += 256) lw[i] = lin_w[i];
  if (threadIdx.x < 16) lb[threadIdx.x] = lin_b[threadIdx.x];
  __syncthreads();
  const int n = blockIdx.x * 256 + threadIdx.x;
  if (n >= N) return;
  float xa[16], xb[16];
  const int r = rank[n];
#pragma unroll
  for (int c = 0; c < 16; c += 4) {
    float4 va = *(const float4*)(x1 + (size_t)n * 16 + c);
    float4 vb = *(const float4*)(c2out + (size_t)r * 16 + c);
    xa[c] = va.x; xa[c + 1] = va.y; xa[c + 2] = va.z; xa[c + 3] = va.w;
    xb[c] = vb.x; xb[c + 1] = vb.y; xb[c + 2] = vb.z; xb[c + 3] = vb.w;
  }
  float z[16];
#pragma unroll
  for (int o = 0; o < 16; ++o) z[o] = lb[o];
#pragma unroll
  for (int c = 0; c < 16; ++c) {
    float va = xa[c], vb = xb[c];
#pragma unroll
    for (int o = 0; o < 16; ++o) z[o] += va * lw[c * 16 + o] + vb * lw[(16 + c) * 16 + o];
  }
  float m = z[0];
#pragma unroll
  for (int o = 1; o < 16; ++o) m = fmaxf(m, z[o]);
  float ssum = 0.f;
#pragma unroll
  for (int o = 0; o < 16; ++o) ssum += expf(z[o] - m);
  float lse = m + logf(ssum);
#pragma unroll
  for (int o = 0; o < 16; ++o) out[(size_t)n * 16 + o] = z[o] - lse;
}

extern "C" void kernel_launch(void* const* d_in, const int* in_sizes, int n_in,
                              void* d_out, int out_size, void* d_ws, size_t ws_size,
                              hipStream_t stream) {
  const float* x = (const float*)d_in[0];
  const int* ei = (const int*)d_in[1];
  const float* W1 = (const float*)d_in[2];
  const float* a_src1 = (const float*)d_in[3];
  const float* a_dst1 = (const float*)d_in[4];
  const float* b1 = (const float*)d_in[5];
  const float* W2 = (const float*)d_in[6];
  const float* a_src2 = (const float*)d_in[7];
  const float* a_dst2 = (const float*)d_in[8];
  const float* b2 = (const float*)d_in[9];
  const float* proj_w = (const float*)d_in[10];
  const float* proj_b = (const float*)d_in[11];
  const float* c1_w = (const float*)d_in[12];
  const float* c1_b = (const float*)d_in[13];
  const float* c2_w = (const float*)d_in[14];
  const float* c2_b = (const float*)d_in[15];
  const float* lin_w = (const float*)d_in[16];
  const float* lin_b = (const float*)d_in[17];
  float* out = (float*)d_out;

  const int N = in_sizes[0] / 256;
  const int E = in_sizes[1] / 2;
  const int Etot = E + N;

  // CSR scan padding: 1024 threads x chunk, chunk multiple of 4
  int chunk = (N + 1023) / 1024;
  chunk = (chunk + 3) & ~3;
  const int Npad = 1024 * chunk;

  char* ws = (char*)d_ws;
  size_t off = 0;
  auto alloc = [&](size_t bytes) -> void* {
    void* p = ws + off;
    off = (off + bytes + 255) & ~(size_t)255;
    return p;
  };
  float* h_lin = (float*)alloc((size_t)N * 256 * 4);
  float* als1 = (float*)alloc((size_t)N * 8 * 4);
  float* ald1 = (float*)alloc((size_t)N * 8 * 4);
  int* counts = (int*)alloc((size_t)Npad * 4);
  int* offsets = (int*)alloc((size_t)(Npad + 1) * 4);
  int* cursor = (int*)alloc((size_t)Npad * 4);
  int* csr_src = (int*)alloc((size_t)Etot * 4);
  float* h2 = (float*)alloc((size_t)N * 16 * 4);
  float* als2 = (float*)alloc((size_t)N * 4);
  float* ald2 = (float*)alloc((size_t)N * 4);
  float* x1 = (float*)alloc((size_t)N * 16 * 4);
  float* gbuf = (float*)alloc((size_t)N * 4);
  unsigned long long* keys = (unsigned long long*)alloc((size_t)N * 8);
  int* bhist = (int*)alloc((size_t)NBUCKET * 4);
  int* boffs = (int*)alloc((size_t)(NBUCKET + 1) * 4);
  int* bcursor = (int*)alloc((size_t)NBUCKET * 4);
  unsigned long long* bkeys = (unsigned long long*)alloc((size_t)N * 8);
  int* rank = (int*)alloc((size_t)N * 4);
  float* sortedv = (float*)alloc((size_t)N * 16 * 4);
  float* c1out = (float*)alloc((size_t)N * 16 * 4);
  float* c2out = (float*)alloc((size_t)N * 16 * 4);
  if (off > ws_size) return;  // fail loudly (poisoned output) rather than corrupt memory

  hipMemsetAsync(counts, 0, (size_t)Npad * 4, stream);
  hipMemsetAsync(bhist, 0, (size_t)NBUCKET * 4, stream);

  dim3 gg((N + 63) / 64, 4);
  k_gemm1<<<gg, 256, 0, stream>>>(x, W1, h_lin, N);
  k_al1<<<(N + 3) / 4, 256, 0, stream>>>(h_lin, a_src1, a_dst1, als1, ald1, N);
  k_hist<<<(Etot + 255) / 256, 256, 0, stream>>>(ei, counts, E, N);
  k_scan<<<1, 1024, 0, stream>>>(counts, offsets, cursor, chunk);
  k_scatter<<<(Etot + 255) / 256, 256, 0, stream>>>(ei, cursor, csr_src, E, N);
  k_gat1<<<(N + 3) / 4, 256, 0, stream>>>(h_lin, als1, ald1, b1, offsets, csr_src,
                                          W2, a_src2, a_dst2, h2, als2, ald2, N);
  k_gat2<<<(N + 3) / 4, 256, 0, stream>>>(h2, als2, ald2, b2, proj_w, proj_b,
                                          offsets, csr_src, x1, gbuf, keys, bhist, N);
  k_scan<<<1, 1024, 0, stream>>>(bhist, boffs, bcursor, NBUCKET / 1024);
  k_bscatter<<<(N + 255) / 256, 256, 0, stream>>>(keys, bcursor, bkeys, N);
  k_brank<<<(N + 255) / 256, 256, 0, stream>>>(bkeys, boffs, gbuf, x1, rank, sortedv, N);
  k_conv<<<(N + 255) / 256, 256, 0, stream>>>(sortedv, c1_w, c1_b, c1out, N, 1);
  k_conv<<<(N + 255) / 256, 256, 0, stream>>>(c1out, c2_w, c2_b, c2out, N, 0);
  k_final<<<(N + 255) / 256, 256, 0, stream>>>(x1, c2out, rank, lin_w, lin_b, out, N);
}

// Round 5
// 536.392 us; speedup vs baseline: 1.5684x; 1.0015x over previous
//
#include <hip/hip_runtime.h>
#include <math.h>

#define NBUCKET 65536
#define CHUNK_SHIFT 12
#define NCHUNK 16  // ceil(50000/4096)=13 used; 16 for alignment

__device__ __forceinline__ float leakyrelu02(float v) { return v > 0.f ? v : 0.2f * v; }

// ============ GEMM: C[M,256] = A[M,256] @ B[256,256], fp32 ============
__global__ __launch_bounds__(256) void k_gemm1(const float* __restrict__ A,
                                               const float* __restrict__ B,
                                               float* __restrict__ C, int M) {
  __shared__ float As[16][68];
  __shared__ float Bs[16][64];
  const int m0 = blockIdx.x * 64;
  const int n0 = blockIdx.y * 64;
  const int tid = threadIdx.x;
  const int tm = tid & 15, tn = tid >> 4;
  float acc[4][4];
#pragma unroll
  for (int i = 0; i < 4; ++i)
#pragma unroll
    for (int j = 0; j < 4; ++j) acc[i][j] = 0.f;

  const int am = tid & 63, ak = (tid >> 6) << 2;
  const int bk = tid >> 4, bn = (tid & 15) << 2;

  for (int k0 = 0; k0 < 256; k0 += 16) {
    float4 av = make_float4(0.f, 0.f, 0.f, 0.f);
    if (m0 + am < M) av = *(const float4*)(A + (size_t)(m0 + am) * 256 + (k0 + ak));
    As[ak + 0][am] = av.x;
    As[ak + 1][am] = av.y;
    As[ak + 2][am] = av.z;
    As[ak + 3][am] = av.w;
    float4 bv = *(const float4*)(B + (size_t)(k0 + bk) * 256 + (n0 + bn));
    *(float4*)&Bs[bk][bn] = bv;
    __syncthreads();
#pragma unroll
    for (int kk = 0; kk < 16; ++kk) {
      float a[4], b[4];
#pragma unroll
      for (int i = 0; i < 4; ++i) a[i] = As[kk][tm * 4 + i];
#pragma unroll
      for (int j = 0; j < 4; ++j) b[j] = Bs[kk][tn * 4 + j];
#pragma unroll
      for (int i = 0; i < 4; ++i)
#pragma unroll
        for (int j = 0; j < 4; ++j) acc[i][j] += a[i] * b[j];
    }
    __syncthreads();
  }
#pragma unroll
  for (int i = 0; i < 4; ++i) {
    int m = m0 + tm * 4 + i;
    if (m < M) {
      float4 o = make_float4(acc[i][0], acc[i][1], acc[i][2], acc[i][3]);
      *(float4*)(C + (size_t)m * 256 + (n0 + tn * 4)) = o;
    }
  }
}

// ============ attention logits for layer 1: wave per node ============
__global__ __launch_bounds__(256) void k_al1(const float* __restrict__ h_lin,
                                             const float* __restrict__ a_src,
                                             const float* __restrict__ a_dst,
                                             float* __restrict__ als,
                                             float* __restrict__ ald, int N) {
  int gid = blockIdx.x * 256 + threadIdx.x;
  int n = gid >> 6;
  int l = threadIdx.x & 63;
  if (n >= N) return;
  float4 h4 = *(const float4*)(h_lin + (size_t)n * 256 + l * 4);
  float4 vs = *(const float4*)(a_src + l * 4);
  float4 vd = *(const float4*)(a_dst + l * 4);
  float ps = h4.x * vs.x + h4.y * vs.y + h4.z * vs.z + h4.w * vs.w;
  float pd = h4.x * vd.x + h4.y * vd.y + h4.z * vd.z + h4.w * vd.w;
  ps += __shfl_xor(ps, 1); pd += __shfl_xor(pd, 1);
  ps += __shfl_xor(ps, 2); pd += __shfl_xor(pd, 2);
  ps += __shfl_xor(ps, 4); pd += __shfl_xor(pd, 4);
  if ((l & 7) == 0) {
    als[(size_t)n * 8 + (l >> 3)] = ps;
    ald[(size_t)n * 8 + (l >> 3)] = pd;
  }
}

// ============ CSR build: histogram over (dst, src-chunk) ============
__global__ __launch_bounds__(256) void k_hist2(const int* __restrict__ ei,
                                               int* __restrict__ counts2, int E, int N) {
  int e = blockIdx.x * 256 + threadIdx.x;
  if (e >= E + N) return;
  int d, s;
  if (e < E) { d = ei[E + e]; s = ei[e]; }
  else { d = e - E; s = d; }
  atomicAdd(&counts2[d * NCHUNK + (s >> CHUNK_SHIFT)], 1);
}

// fold per-(dst,chunk) counts to per-dst counts
__global__ __launch_bounds__(256) void k_fold(const int* __restrict__ counts2,
                                              int* __restrict__ counts, int N) {
  int d = blockIdx.x * 256 + threadIdx.x;
  if (d >= N) return;
  int s = 0;
#pragma unroll
  for (int i = 0; i < NCHUNK; i += 4) {
    int4 v = *(const int4*)(counts2 + (size_t)d * NCHUNK + i);
    s += v.x + v.y + v.z + v.w;
  }
  counts[d] = s;
}

// expand per-dst offsets to per-(dst,chunk) cursors
__global__ __launch_bounds__(256) void k_expand(const int* __restrict__ offsets,
                                                const int* __restrict__ counts2,
                                                int* __restrict__ cursor2, int N) {
  int d = blockIdx.x * 256 + threadIdx.x;
  if (d >= N) return;
  int run = offsets[d];
#pragma unroll
  for (int i = 0; i < NCHUNK; i += 4) {
    int4 v = *(const int4*)(counts2 + (size_t)d * NCHUNK + i);
    int4 o;
    o.x = run; run += v.x;
    o.y = run; run += v.y;
    o.z = run; run += v.z;
    o.w = run; run += v.w;
    *(int4*)(cursor2 + (size_t)d * NCHUNK + i) = o;
  }
}

// scan over Npad = 1024*chunk entries (chunk multiple of 4, counts padded+zeroed)
__global__ __launch_bounds__(1024) void k_scan(const int* __restrict__ counts,
                                               int* __restrict__ offsets,
                                               int* __restrict__ cursor, int chunk) {
  __shared__ int part[1024];
  const int t = threadIdx.x;
  const int base = t * chunk;
  int ssum = 0;
  for (int i = 0; i < chunk; i += 4) {
    int4 v = *(const int4*)(counts + base + i);
    ssum += v.x + v.y + v.z + v.w;
  }
  part[t] = ssum;
  __syncthreads();
  for (int d = 1; d < 1024; d <<= 1) {
    int v = (t >= d) ? part[t - d] : 0;
    __syncthreads();
    part[t] += v;
    __syncthreads();
  }
  int run = (t == 0) ? 0 : part[t - 1];
  for (int i = 0; i < chunk; i += 4) {
    int4 v = *(const int4*)(counts + base + i);
    int4 o;
    o.x = run; run += v.x;
    o.y = run; run += v.y;
    o.z = run; run += v.z;
    o.w = run; run += v.w;
    *(int4*)(offsets + base + i) = o;
    if (cursor) *(int4*)(cursor + base + i) = o;
  }
  if (t == 1023) offsets[1024 * chunk] = run;
}

// ============ scatter edges (chunk-ordered within dst) + precompute layer-1 edge weights ============
__global__ __launch_bounds__(256) void k_scatter_ew(
    const int* __restrict__ ei, const float* __restrict__ als1,
    const float* __restrict__ ald1, int* __restrict__ cursor2,
    int* __restrict__ csr_src, int* __restrict__ csr_dst,
    float* __restrict__ ew, int E, int N) {
  int e = blockIdx.x * 256 + threadIdx.x;
  if (e >= E + N) return;
  int d, s;
  if (e < E) { d = ei[E + e]; s = ei[e]; }
  else { d = e - E; s = d; }
  int pos = atomicAdd(&cursor2[d * NCHUNK + (s >> CHUNK_SHIFT)], 1);
  csr_src[pos] = s;
  csr_dst[pos] = d;
  float4 as0 = *(const float4*)(als1 + (size_t)s * 8);
  float4 as1 = *(const float4*)(als1 + (size_t)s * 8 + 4);
  float4 ad0 = *(const float4*)(ald1 + (size_t)d * 8);
  float4 ad1 = *(const float4*)(ald1 + (size_t)d * 8 + 4);
  float4 w0, w1;
  w0.x = expf(leakyrelu02(as0.x + ad0.x));
  w0.y = expf(leakyrelu02(as0.y + ad0.y));
  w0.z = expf(leakyrelu02(as0.z + ad0.z));
  w0.w = expf(leakyrelu02(as0.w + ad0.w));
  w1.x = expf(leakyrelu02(as1.x + ad1.x));
  w1.y = expf(leakyrelu02(as1.y + ad1.y));
  w1.z = expf(leakyrelu02(as1.z + ad1.z));
  w1.w = expf(leakyrelu02(as1.w + ad1.w));
  *(float4*)(ew + (size_t)pos * 8) = w0;
  *(float4*)(ew + (size_t)pos * 8 + 4) = w1;
}

// ============ layer-2 edge weights, edge-parallel ============
__global__ __launch_bounds__(256) void k_ew2(const int* __restrict__ csr_src,
                                             const int* __restrict__ csr_dst,
                                             const float* __restrict__ als2,
                                             const float* __restrict__ ald2,
                                             float* __restrict__ ew2, int Etot) {
  int t = blockIdx.x * 256 + threadIdx.x;
  if (t >= Etot) return;
  ew2[t] = expf(leakyrelu02(als2[csr_src[t]] + ald2[csr_dst[t]]));
}

// ============ GAT layer 1: single-pass weighted aggregation (weights precomputed) +
// fused (relu row) @ W2 -> h2, al2 ============
__global__ __launch_bounds__(256) void k_gat1(
    const float* __restrict__ h_lin, const float* __restrict__ ew,
    const float* __restrict__ b1, const int* __restrict__ offsets,
    const int* __restrict__ csr_src, const float* __restrict__ W2,
    const float* __restrict__ a_src2, const float* __restrict__ a_dst2,
    float* __restrict__ h2, float* __restrict__ als2, float* __restrict__ ald2, int N) {
  __shared__ float w2s[4352];  // [cc]*17 + o
  __shared__ float rowbuf[4][256];
  for (int i = threadIdx.x; i < 4096; i += 256) w2s[(i >> 4) * 17 + (i & 15)] = W2[i];
  __syncthreads();

  const int w = threadIdx.x >> 6;
  const int l = threadIdx.x & 63;
  const int n = blockIdx.x * 4 + w;
  if (n >= N) return;

  const int off = offsets[n];
  const int deg = offsets[n + 1] - off;

  const int h3 = l >> 3;  // head owning this lane's 4 channels
  const float* hb = h_lin + l * 4;

  float ax = 0.f, ay = 0.f, az = 0.f, aw2 = 0.f, sw = 0.f;
  int e = 0;
  for (; e + 4 <= deg; e += 4) {
    int p = off + e;
    int s0 = csr_src[p + 0];
    int s1 = csr_src[p + 1];
    int s2 = csr_src[p + 2];
    int s3 = csr_src[p + 3];
    float w0 = ew[(size_t)(p + 0) * 8 + h3];
    float w1 = ew[(size_t)(p + 1) * 8 + h3];
    float w2v = ew[(size_t)(p + 2) * 8 + h3];
    float w3 = ew[(size_t)(p + 3) * 8 + h3];
    float4 r0 = *(const float4*)(hb + (size_t)s0 * 256);
    float4 r1 = *(const float4*)(hb + (size_t)s1 * 256);
    float4 r2 = *(const float4*)(hb + (size_t)s2 * 256);
    float4 r3 = *(const float4*)(hb + (size_t)s3 * 256);
    sw += (w0 + w1) + (w2v + w3);
    ax += w0 * r0.x + w1 * r1.x + w2v * r2.x + w3 * r3.x;
    ay += w0 * r0.y + w1 * r1.y + w2v * r2.y + w3 * r3.y;
    az += w0 * r0.z + w1 * r1.z + w2v * r2.z + w3 * r3.z;
    aw2 += w0 * r0.w + w1 * r1.w + w2v * r2.w + w3 * r3.w;
  }
  for (; e < deg; ++e) {
    int p = off + e;
    int s = csr_src[p];
    float ww = ew[(size_t)p * 8 + h3];
    float4 r = *(const float4*)(hb + (size_t)s * 256);
    sw += ww;
    ax += ww * r.x; ay += ww * r.y; az += ww * r.z; aw2 += ww * r.w;
  }
  const float inv = 1.f / (sw + 1e-16f);

  float4 bb = *(const float4*)(b1 + l * 4);
  rowbuf[w][l * 4 + 0] = fmaxf(ax * inv + bb.x, 0.f);
  rowbuf[w][l * 4 + 1] = fmaxf(ay * inv + bb.y, 0.f);
  rowbuf[w][l * 4 + 2] = fmaxf(az * inv + bb.z, 0.f);
  rowbuf[w][l * 4 + 3] = fmaxf(aw2 * inv + bb.w, 0.f);
  asm volatile("s_waitcnt lgkmcnt(0)" ::: "memory");

  // h2[n,o] = sum_cc relu_row[cc] * W2[cc,o]; grp-rotated walk
  const int o = l & 15;
  const int grp = l >> 4;
  float a2 = 0.f;
#pragma unroll 8
  for (int t = 0; t < 64; ++t) {
    int cc = grp * 64 + ((t + grp * 8) & 63);
    a2 += rowbuf[w][cc] * w2s[cc * 17 + o];
  }
  a2 += __shfl_xor(a2, 16);
  a2 += __shfl_xor(a2, 32);

  if (l < 16) {
    h2[(size_t)n * 16 + l] = a2;
    float ps = a2 * a_src2[l];
    float pd = a2 * a_dst2[l];
    ps += __shfl_xor(ps, 1); pd += __shfl_xor(pd, 1);
    ps += __shfl_xor(ps, 2); pd += __shfl_xor(pd, 2);
    ps += __shfl_xor(ps, 4); pd += __shfl_xor(pd, 4);
    ps += __shfl_xor(ps, 8); pd += __shfl_xor(pd, 8);
    if (l == 0) { als2[n] = ps; ald2[n] = pd; }
  }
}

// ============ GAT layer 2: single-pass aggregation -> x1, g, keys + bucket hist ============
__global__ __launch_bounds__(256) void k_gat2(
    const float* __restrict__ h2, const float* __restrict__ ew2,
    const float* __restrict__ b2, const float* __restrict__ proj_w,
    const float* __restrict__ proj_b, const int* __restrict__ offsets,
    const int* __restrict__ csr_src, float* __restrict__ x1,
    float* __restrict__ g, unsigned long long* __restrict__ keys,
    int* __restrict__ bhist, int N) {
  const int w = threadIdx.x >> 6;
  const int l = threadIdx.x & 63;
  const int n = blockIdx.x * 4 + w;
  if (n >= N) return;
  const int off = offsets[n];
  const int deg = offsets[n + 1] - off;
  const int slot = l >> 4;  // 4 parallel edge slots
  const int c = l & 15;

  float acc = 0.f, sw = 0.f;
  int e0 = 0;
  for (; e0 + 8 <= deg; e0 += 8) {
    int pA = off + e0 + slot;
    int pB = off + e0 + 4 + slot;
    int sA = csr_src[pA];
    int sB = csr_src[pB];
    float wA = ew2[pA];
    float wB = ew2[pB];
    float hA = h2[(size_t)sA * 16 + c];
    float hB = h2[(size_t)sB * 16 + c];
    sw += wA + wB;
    acc += wA * hA + wB * hB;
  }
  for (; e0 < deg; e0 += 4) {
    int e = e0 + slot;
    if (e < deg) {
      int p = off + e;
      int s = csr_src[p];
      float v = ew2[p];
      sw += v;
      acc += v * h2[(size_t)s * 16 + c];
    }
  }
  acc += __shfl_xor(acc, 16); sw += __shfl_xor(sw, 16);
  acc += __shfl_xor(acc, 32); sw += __shfl_xor(sw, 32);
  float x1v = acc / (sw + 1e-16f) + b2[c];

  float pg = x1v * proj_w[c];
  pg += __shfl_xor(pg, 1);
  pg += __shfl_xor(pg, 2);
  pg += __shfl_xor(pg, 4);
  pg += __shfl_xor(pg, 8);
  if (l < 16) x1[(size_t)n * 16 + l] = x1v;
  if (l == 0) {
    float gv = pg + proj_b[0];
    g[n] = gv;
    unsigned u = __float_as_uint(gv);
    u = (u & 0x80000000u) ? ~u : (u | 0x80000000u);
    keys[n] = (((unsigned long long)u) << 32) | (unsigned)n;
    atomicAdd(&bhist[u >> 16], 1);
  }
}

// ============ bucket scatter ============
__global__ __launch_bounds__(256) void k_bscatter(const unsigned long long* __restrict__ keys,
                                                  int* __restrict__ cursor,
                                                  unsigned long long* __restrict__ bkeys, int N) {
  int n = blockIdx.x * 256 + threadIdx.x;
  if (n >= N) return;
  unsigned long long k = keys[n];
  int b = (int)(k >> 48);
  int pos = atomicAdd(&cursor[b], 1);
  bkeys[pos] = k;
}

// ============ exact stable rank within bucket + scatter g*x1 to sorted order ============
__global__ __launch_bounds__(256) void k_brank(const unsigned long long* __restrict__ bkeys,
                                               const int* __restrict__ boffs,
                                               const float* __restrict__ g,
                                               const float* __restrict__ x1,
                                               int* __restrict__ rank,
                                               float* __restrict__ sortedv, int N) {
  int pos = blockIdx.x * 256 + threadIdx.x;
  if (pos >= N) return;
  unsigned long long k = bkeys[pos];
  int b = (int)(k >> 48);
  int lo = boffs[b], hi = boffs[b + 1];
  int r = lo;
  for (int j = lo; j < hi; ++j) r += (bkeys[j] < k) ? 1 : 0;
  int idx = (int)(unsigned)(k & 0xffffffffull);
  rank[idx] = r;
  float gv = g[idx];
#pragma unroll
  for (int c = 0; c < 16; c += 4) {
    float4 v = *(const float4*)(x1 + (size_t)idx * 16 + c);
    float4 o = make_float4(gv * v.x, gv * v.y, gv * v.z, gv * v.w);
    *(float4*)(sortedv + (size_t)r * 16 + c) = o;
  }
}

// ============ conv1d 'same', K=5, 16->16 channels ============
__global__ __launch_bounds__(256) void k_conv(const float* __restrict__ in,
                                              const float* __restrict__ wgt,
                                              const float* __restrict__ bias,
                                              float* __restrict__ out, int N, int relu) {
  __shared__ float s[260][17];
  __shared__ float ws[1280];
  __shared__ float bs[16];
  const int p0 = blockIdx.x * 256;
  for (int i = threadIdx.x; i < 1280; i += 256) ws[i] = wgt[i];
  if (threadIdx.x < 16) bs[threadIdx.x] = bias[threadIdx.x];
  for (int idx = threadIdx.x; idx < 260 * 16; idx += 256) {
    int lp = idx >> 4, c = idx & 15;
    int gp = p0 - 2 + lp;
    s[lp][c] = (gp >= 0 && gp < N) ? in[(size_t)gp * 16 + c] : 0.f;
  }
  __syncthreads();
  const int p = p0 + threadIdx.x;
  if (p >= N) return;
  float acc[16];
#pragma unroll
  for (int o = 0; o < 16; ++o) acc[o] = bs[o];
  for (int k = 0; k < 5; ++k) {
    for (int c = 0; c < 16; ++c) {
      float xv = s[threadIdx.x + k][c];
#pragma unroll
      for (int o = 0; o < 16; ++o) acc[o] += ws[(o * 16 + c) * 5 + k] * xv;
    }
  }
#pragma unroll
  for (int o = 0; o < 16; ++o) {
    float v = acc[o];
    if (relu) v = fmaxf(v, 0.f);
    out[(size_t)p * 16 + o] = v;
  }
}

// ============ final: concat(x1, x2=conv2[rank]) @ lin_w + lin_b -> log_softmax ============
__global__ __launch_bounds__(256) void k_final(
    const float* __restrict__ x1, const float* __restrict__ c2out,
    const int* __restrict__ rank, const float* __restrict__ lin_w,
    const float* __restrict__ lin_b, float* __restrict__ out, int N) {
  __shared__ float lw[512];
  __shared__ float lb[16];
  for (int i = threadIdx.x; i < 512; i += 256) lw[i] = lin_w[i];
  if (threadIdx.x < 16) lb[threadIdx.x] = lin_b[threadIdx.x];
  __syncthreads();
  const int n = blockIdx.x * 256 + threadIdx.x;
  if (n >= N) return;
  float xa[16], xb[16];
  const int r = rank[n];
#pragma unroll
  for (int c = 0; c < 16; c += 4) {
    float4 va = *(const float4*)(x1 + (size_t)n * 16 + c);
    float4 vb = *(const float4*)(c2out + (size_t)r * 16 + c);
    xa[c] = va.x; xa[c + 1] = va.y; xa[c + 2] = va.z; xa[c + 3] = va.w;
    xb[c] = vb.x; xb[c + 1] = vb.y; xb[c + 2] = vb.z; xb[c + 3] = vb.w;
  }
  float z[16];
#pragma unroll
  for (int o = 0; o < 16; ++o) z[o] = lb[o];
#pragma unroll
  for (int c = 0; c < 16; ++c) {
    float va = xa[c], vb = xb[c];
#pragma unroll
    for (int o = 0; o < 16; ++o) z[o] += va * lw[c * 16 + o] + vb * lw[(16 + c) * 16 + o];
  }
  float m = z[0];
#pragma unroll
  for (int o = 1; o < 16; ++o) m = fmaxf(m, z[o]);
  float ssum = 0.f;
#pragma unroll
  for (int o = 0; o < 16; ++o) ssum += expf(z[o] - m);
  float lse = m + logf(ssum);
#pragma unroll
  for (int o = 0; o < 16; ++o) out[(size_t)n * 16 + o] = z[o] - lse;
}

extern "C" void kernel_launch(void* const* d_in, const int* in_sizes, int n_in,
                              void* d_out, int out_size, void* d_ws, size_t ws_size,
                              hipStream_t stream) {
  const float* x = (const float*)d_in[0];
  const int* ei = (const int*)d_in[1];
  const float* W1 = (const float*)d_in[2];
  const float* a_src1 = (const float*)d_in[3];
  const float* a_dst1 = (const float*)d_in[4];
  const float* b1 = (const float*)d_in[5];
  const float* W2 = (const float*)d_in[6];
  const float* a_src2 = (const float*)d_in[7];
  const float* a_dst2 = (const float*)d_in[8];
  const float* b2 = (const float*)d_in[9];
  const float* proj_w = (const float*)d_in[10];
  const float* proj_b = (const float*)d_in[11];
  const float* c1_w = (const float*)d_in[12];
  const float* c1_b = (const float*)d_in[13];
  const float* c2_w = (const float*)d_in[14];
  const float* c2_b = (const float*)d_in[15];
  const float* lin_w = (const float*)d_in[16];
  const float* lin_b = (const float*)d_in[17];
  float* out = (float*)d_out;

  const int N = in_sizes[0] / 256;
  const int E = in_sizes[1] / 2;
  const int Etot = E + N;

  // CSR scan padding: 1024 threads x chunk, chunk multiple of 4
  int chunk = (N + 1023) / 1024;
  chunk = (chunk + 3) & ~3;
  const int Npad = 1024 * chunk;

  char* ws = (char*)d_ws;
  size_t off = 0;
  auto alloc = [&](size_t bytes) -> void* {
    void* p = ws + off;
    off = (off + bytes + 255) & ~(size_t)255;
    return p;
  };
  float* h_lin = (float*)alloc((size_t)N * 256 * 4);
  float* als1 = (float*)alloc((size_t)N * 8 * 4);
  float* ald1 = (float*)alloc((size_t)N * 8 * 4);
  int* counts = (int*)alloc((size_t)Npad * 4);
  int* offsets = (int*)alloc((size_t)(Npad + 1) * 4);
  int* counts2 = (int*)alloc((size_t)N * NCHUNK * 4);
  int* cursor2 = (int*)alloc((size_t)N * NCHUNK * 4);
  int* csr_src = (int*)alloc((size_t)Etot * 4);
  int* csr_dst = (int*)alloc((size_t)Etot * 4);
  float* ew = (float*)alloc((size_t)Etot * 8 * 4);
  float* ew2 = (float*)alloc((size_t)Etot * 4);
  float* h2 = (float*)alloc((size_t)N * 16 * 4);
  float* als2 = (float*)alloc((size_t)N * 4);
  float* ald2 = (float*)alloc((size_t)N * 4);
  float* x1 = (float*)alloc((size_t)N * 16 * 4);
  float* gbuf = (float*)alloc((size_t)N * 4);
  unsigned long long* keys = (unsigned long long*)alloc((size_t)N * 8);
  int* bhist = (int*)alloc((size_t)NBUCKET * 4);
  int* boffs = (int*)alloc((size_t)(NBUCKET + 1) * 4);
  int* bcursor = (int*)alloc((size_t)NBUCKET * 4);
  unsigned long long* bkeys = (unsigned long long*)alloc((size_t)N * 8);
  int* rank = (int*)alloc((size_t)N * 4);
  float* sortedv = (float*)alloc((size_t)N * 16 * 4);
  float* c1out = (float*)alloc((size_t)N * 16 * 4);
  float* c2out = (float*)alloc((size_t)N * 16 * 4);
  if (off > ws_size) return;  // fail loudly rather than corrupt memory

  hipMemsetAsync(counts, 0, (size_t)Npad * 4, stream);
  hipMemsetAsync(counts2, 0, (size_t)N * NCHUNK * 4, stream);
  hipMemsetAsync(bhist, 0, (size_t)NBUCKET * 4, stream);

  dim3 gg((N + 63) / 64, 4);
  k_gemm1<<<gg, 256, 0, stream>>>(x, W1, h_lin, N);
  k_al1<<<(N + 3) / 4, 256, 0, stream>>>(h_lin, a_src1, a_dst1, als1, ald1, N);
  k_hist2<<<(Etot + 255) / 256, 256, 0, stream>>>(ei, counts2, E, N);
  k_fold<<<(N + 255) / 256, 256, 0, stream>>>(counts2, counts, N);
  k_scan<<<1, 1024, 0, stream>>>(counts, offsets, nullptr, chunk);
  k_expand<<<(N + 255) / 256, 256, 0, stream>>>(offsets, counts2, cursor2, N);
  k_scatter_ew<<<(Etot + 255) / 256, 256, 0, stream>>>(ei, als1, ald1, cursor2,
                                                       csr_src, csr_dst, ew, E, N);
  k_gat1<<<(N + 3) / 4, 256, 0, stream>>>(h_lin, ew, b1, offsets, csr_src,
                                          W2, a_src2, a_dst2, h2, als2, ald2, N);
  k_ew2<<<(Etot + 255) / 256, 256, 0, stream>>>(csr_src, csr_dst, als2, ald2, ew2, Etot);
  k_gat2<<<(N + 3) / 4, 256, 0, stream>>>(h2, ew2, b2, proj_w, proj_b,
                                          offsets, csr_src, x1, gbuf, keys, bhist, N);
  k_scan<<<1, 1024, 0, stream>>>(bhist, boffs, bcursor, NBUCKET / 1024);
  k_bscatter<<<(N + 255) / 256, 256, 0, stream>>>(keys, bcursor, bkeys, N);
  k_brank<<<(N + 255) / 256, 256, 0, stream>>>(bkeys, boffs, gbuf, x1, rank, sortedv, N);
  k_conv<<<(N + 255) / 256, 256, 0, stream>>>(sortedv, c1_w, c1_b, c1out, N, 1);
  k_conv<<<(N + 255) / 256, 256, 0, stream>>>(c1out, c2_w, c2_b, c2out, N, 0);
  k_final<<<(N + 255) / 256, 256, 0, stream>>>(x1, c2out, rank, lin_w, lin_b, out, N);
}